// Round 1
// baseline (1325.630 us; speedup 1.0000x reference)
//
#include <hip/hip_runtime.h>
#include <hip/hip_bf16.h>

#define Bb 16
#define Lq 2048
#define Hh 256
#define Nst 64
#define NLay 4
#define IND 40
#define OUTD 33

__device__ __forceinline__ float sigmoidf_(float x) {
    return 1.0f / (1.0f + __expf(-x));
}
__device__ __forceinline__ float gelu_(float x) {
    // tanh-approx gelu == x * sigmoid(2*sqrt(2/pi)*(x + 0.044715 x^3))
    float x2 = x * x;
    float u = x * fmaf(0.0713548162726f, x2, 1.5957691216057308f);
    return x * sigmoidf_(u);
}
__device__ __forceinline__ float dot4acc(float4 a, float4 b, float acc) {
    acc = fmaf(a.x, b.x, acc); acc = fmaf(a.y, b.y, acc);
    acc = fmaf(a.z, b.z, acc); acc = fmaf(a.w, b.w, acc);
    return acc;
}

// ---------------- encoder: h[t,hh] = x[t,:40] . enc_w[hh,:40] + enc_b ----------------
__global__ __launch_bounds__(256) void enc_kernel(const float* __restrict__ x,
                                                  const float* __restrict__ enc_w,
                                                  const float* __restrict__ enc_b,
                                                  float* __restrict__ h) {
    __shared__ float xs[8 * IND];
    int tid = threadIdx.x;
    int t0 = blockIdx.x * 8;
    for (int i = tid; i < 8 * IND; i += 256) xs[i] = x[t0 * IND + i];
    float w[IND];
    const float4* w4 = (const float4*)(enc_w + tid * IND);
#pragma unroll
    for (int c = 0; c < 10; ++c) {
        float4 v = w4[c];
        w[4 * c] = v.x; w[4 * c + 1] = v.y; w[4 * c + 2] = v.z; w[4 * c + 3] = v.w;
    }
    float bias = enc_b[tid];
    __syncthreads();
#pragma unroll
    for (int t = 0; t < 8; ++t) {
        float acc = bias;
#pragma unroll
        for (int i = 0; i < IND; ++i) acc = fmaf(xs[t * IND + i], w[i], acc);
        h[(t0 + t) * Hh + tid] = acc;
    }
}

// ---------------- layernorm: one wave per token ----------------
__global__ __launch_bounds__(256) void ln_kernel(const float* __restrict__ h,
                                                 float* __restrict__ z,
                                                 const float* __restrict__ scale,
                                                 const float* __restrict__ bias) {
    int lane = threadIdx.x & 63;
    int wid = threadIdx.x >> 6;
    int t = blockIdx.x * 4 + wid;
    const float4* row = (const float4*)(h + (size_t)t * Hh);
    float4 v = row[lane];
    float s = (v.x + v.y) + (v.z + v.w);
    float q = fmaf(v.x, v.x, fmaf(v.y, v.y, fmaf(v.z, v.z, v.w * v.w)));
#pragma unroll
    for (int m = 1; m < 64; m <<= 1) {
        s += __shfl_xor(s, m, 64);
        q += __shfl_xor(q, m, 64);
    }
    float mu = s * (1.0f / 256.0f);
    float var = q * (1.0f / 256.0f) - mu * mu;
    float rs = rsqrtf(var + 1e-5f);
    float4 sc = ((const float4*)scale)[lane];
    float4 bi = ((const float4*)bias)[lane];
    float4 o;
    o.x = fmaf((v.x - mu) * rs, sc.x, bi.x);
    o.y = fmaf((v.y - mu) * rs, sc.y, bi.y);
    o.z = fmaf((v.z - mu) * rs, sc.z, bi.z);
    o.w = fmaf((v.w - mu) * rs, sc.w, bi.w);
    ((float4*)(z + (size_t)t * Hh))[lane] = o;
}

// ---------------- SSM scan: one wave per (b,h), lane = state n; in-place z->y ----------------
// y[l] = gelu( 2*Re(sum_n CdB_n * s_n[l]) + d_h * z[l] ),  s[l] = dA*s[l-1] + z[l]
__global__ __launch_bounds__(256) void scan_kernel(float* __restrict__ zy,
                                                   const float* __restrict__ lre_p,
                                                   const float* __restrict__ lim_p,
                                                   const float* __restrict__ cre_p,
                                                   const float* __restrict__ cim_p,
                                                   const float* __restrict__ d_p,
                                                   const float* __restrict__ ls_p) {
    __shared__ float pbuf[4][64][68];
    __shared__ float zbf[4][64];
    int lane = threadIdx.x & 63;
    int wid = threadIdx.x >> 6;
    // XCD-aware swizzle: keep line-sharing (adjacent-h) blocks on one XCD
    int p = blockIdx.x;
    int lt = ((p & 7) << 7) | (p >> 3);   // bijective for 1024 blocks
    int w = lt * 4 + wid;                 // 0..4095
    int b = w >> 8;
    int hh = w & 255;

    int pidx = hh * Nst + lane;
    float lre = lre_p[pidx], lim = lim_p[pidx];
    float cre = cre_p[pidx], cim = cim_p[pidx];
    float dt = expf(ls_p[hh]);
    float dh = d_p[hh];
    float er = expf(lre * dt);
    float th = lim * dt;
    float dAre = er * cosf(th);
    float dAim = er * sinf(th);
    float inv = 1.0f / (lre * lre + lim * lim);
    float dBre = ((dAre - 1.0f) * lre + dAim * lim) * inv;
    float dBim = (dAim * lre - (dAre - 1.0f) * lim) * inv;
    float kr = 2.0f * (cre * dBre - cim * dBim);
    float ki = 2.0f * (cre * dBim + cim * dBre);

    float sre = 0.0f, sim = 0.0f;
    float(*pb)[68] = pbuf[wid];
    float* zb = zbf[wid];
    size_t base = ((size_t)b * Lq) * Hh + hh;

    for (int tt = 0; tt < Lq / 64; ++tt) {
        float zt = zy[base + (size_t)(tt * 64 + lane) * Hh];
        zb[lane] = zt;
#pragma unroll
        for (int l = 0; l < 64; ++l) {
            float zl = zb[l];
            float nre = fmaf(dAre, sre, fmaf(-dAim, sim, zl));
            float nim = fmaf(dAre, sim, dAim * sre);
            sre = nre; sim = nim;
            pb[l][lane] = fmaf(kr, sre, -ki * sim);
        }
        // transpose-sum: lane t sums its row over all 64 states
        float acc = 0.0f;
        const float4* prow = (const float4*)pb[lane];
#pragma unroll
        for (int c = 0; c < 16; ++c) {
            float4 r = prow[c];
            acc += (r.x + r.y) + (r.z + r.w);
        }
        float y = fmaf(dh, zt, acc);
        zy[base + (size_t)(tt * 64 + lane) * Hh] = gelu_(y);
    }
}

// ---------------- gated matmul + residual: h += (y@W1^T+b1) * sigmoid(y@W2^T+b2) ----------------
__global__ __launch_bounds__(256) void gated_kernel(const float* __restrict__ y,
                                                    const float* __restrict__ w1,
                                                    const float* __restrict__ b1,
                                                    const float* __restrict__ w2,
                                                    const float* __restrict__ b2,
                                                    float* __restrict__ h) {
    __shared__ float a_lds[64][20];
    __shared__ float w1_lds[64][20];
    __shared__ float w2_lds[64][20];
    int tid = threadIdx.x;
    size_t t0 = (size_t)blockIdx.x * 64;
    int g0 = blockIdx.y * 64;
    int si = tid >> 2, sc = (tid & 3) * 4;
    int ti = tid & 15, gi = tid >> 4;
    float acc1[4][4] = {{0}}, acc2[4][4] = {{0}};

    for (int kt = 0; kt < 16; ++kt) {
        int k0 = kt * 16;
        float4 av = *(const float4*)&y[(t0 + si) * Hh + k0 + sc];
        float4 w1v = *(const float4*)&w1[(size_t)(g0 + si) * Hh + k0 + sc];
        float4 w2v = *(const float4*)&w2[(size_t)(g0 + si) * Hh + k0 + sc];
        __syncthreads();
        *(float4*)&a_lds[si][sc] = av;
        *(float4*)&w1_lds[si][sc] = w1v;
        *(float4*)&w2_lds[si][sc] = w2v;
        __syncthreads();
#pragma unroll
        for (int q = 0; q < 4; ++q) {
            float4 af[4], f1[4], f2[4];
#pragma unroll
            for (int r = 0; r < 4; ++r) {
                af[r] = *(const float4*)&a_lds[4 * ti + r][4 * q];
                f1[r] = *(const float4*)&w1_lds[4 * gi + r][4 * q];
                f2[r] = *(const float4*)&w2_lds[4 * gi + r][4 * q];
            }
#pragma unroll
            for (int r = 0; r < 4; ++r)
#pragma unroll
                for (int c = 0; c < 4; ++c) {
                    acc1[r][c] = dot4acc(af[r], f1[c], acc1[r][c]);
                    acc2[r][c] = dot4acc(af[r], f2[c], acc2[r][c]);
                }
        }
    }
    float bb1[4], bb2[4];
#pragma unroll
    for (int c = 0; c < 4; ++c) {
        bb1[c] = b1[g0 + 4 * gi + c];
        bb2[c] = b2[g0 + 4 * gi + c];
    }
#pragma unroll
    for (int r = 0; r < 4; ++r) {
        size_t row = t0 + 4 * ti + r;
        float4 hv = *(float4*)&h[row * Hh + g0 + 4 * gi];
        float p1, p2;
        p1 = acc1[r][0] + bb1[0]; p2 = acc2[r][0] + bb2[0]; hv.x = fmaf(p1, sigmoidf_(p2), hv.x);
        p1 = acc1[r][1] + bb1[1]; p2 = acc2[r][1] + bb2[1]; hv.y = fmaf(p1, sigmoidf_(p2), hv.y);
        p1 = acc1[r][2] + bb1[2]; p2 = acc2[r][2] + bb2[2]; hv.z = fmaf(p1, sigmoidf_(p2), hv.z);
        p1 = acc1[r][3] + bb1[3]; p2 = acc2[r][3] + bb2[3]; hv.w = fmaf(p1, sigmoidf_(p2), hv.w);
        *(float4*)&h[row * Hh + g0 + 4 * gi] = hv;
    }
}

// ---------------- decoder: out[t,o] = h[t,:] . dec_w[o,:] + dec_b[o] ----------------
__global__ __launch_bounds__(256) void dec_kernel(const float* __restrict__ h,
                                                  const float* __restrict__ dec_w,
                                                  const float* __restrict__ dec_b,
                                                  float* __restrict__ out) {
    __shared__ float wT[256][36];
    __shared__ float hs[64][20];
    int tid = threadIdx.x;
    for (int idx = tid; idx < OUTD * Hh; idx += 256) {
        int o = idx >> 8, k = idx & 255;
        wT[k][o] = dec_w[idx];
    }
    size_t t0 = (size_t)blockIdx.x * 64;
    int tl = tid & 63, og = tid >> 6;
    float acc[9];
#pragma unroll
    for (int j = 0; j < 9; ++j) acc[j] = 0.0f;
    int i = tid >> 2, c = (tid & 3) * 4;
    for (int kt = 0; kt < 16; ++kt) {
        __syncthreads();
        *(float4*)&hs[i][c] = *(const float4*)&h[(t0 + i) * Hh + kt * 16 + c];
        __syncthreads();
#pragma unroll
        for (int k2 = 0; k2 < 16; ++k2) {
            float a = hs[tl][k2];
            int kk = kt * 16 + k2;
#pragma unroll
            for (int j = 0; j < 9; ++j) {
                acc[j] = fmaf(a, wT[kk][og + 4 * j], acc[j]);
            }
        }
    }
#pragma unroll
    for (int j = 0; j < 9; ++j) {
        int o = og + 4 * j;
        if (o < OUTD) out[(t0 + tl) * OUTD + o] = acc[j] + dec_b[o];
    }
}

extern "C" void kernel_launch(void* const* d_in, const int* in_sizes, int n_in,
                              void* d_out, int out_size, void* d_ws, size_t ws_size,
                              hipStream_t stream) {
    const float* x = (const float*)d_in[0];
    const float* enc_w = (const float*)d_in[1];
    const float* enc_b = (const float*)d_in[2];
    const float* lre = (const float*)d_in[3];
    const float* lim = (const float*)d_in[4];
    const float* cre = (const float*)d_in[5];
    const float* cim = (const float*)d_in[6];
    const float* dd = (const float*)d_in[7];
    const float* ls = (const float*)d_in[8];
    const float* lns = (const float*)d_in[9];
    const float* lnb = (const float*)d_in[10];
    const float* w1 = (const float*)d_in[11];
    const float* b1 = (const float*)d_in[12];
    const float* w2 = (const float*)d_in[13];
    const float* b2 = (const float*)d_in[14];
    const float* dw = (const float*)d_in[15];
    const float* db = (const float*)d_in[16];
    float* out = (float*)d_out;

    float* hbuf = (float*)d_ws;                       // B*L*H floats
    float* zbuf = hbuf + (size_t)Bb * Lq * Hh;        // B*L*H floats

    enc_kernel<<<(Bb * Lq) / 8, 256, 0, stream>>>(x, enc_w, enc_b, hbuf);
    for (int il = 0; il < NLay; ++il) {
        ln_kernel<<<(Bb * Lq) / 4, 256, 0, stream>>>(hbuf, zbuf, lns + il * Hh, lnb + il * Hh);
        scan_kernel<<<1024, 256, 0, stream>>>(zbuf,
                                              lre + il * Hh * Nst, lim + il * Hh * Nst,
                                              cre + il * Hh * Nst, cim + il * Hh * Nst,
                                              dd + il * Hh, ls + il * Hh);
        gated_kernel<<<dim3((Bb * Lq) / 64, Hh / 64), 256, 0, stream>>>(
            zbuf, w1 + il * Hh * Hh, b1 + il * Hh, w2 + il * Hh * Hh, b2 + il * Hh, hbuf);
    }
    dec_kernel<<<(Bb * Lq) / 64, 256, 0, stream>>>(hbuf, dw, db, out);
}

// Round 2
// 831.934 us; speedup vs baseline: 1.5934x; 1.5934x over previous
//
#include <hip/hip_runtime.h>
#include <hip/hip_bf16.h>

#define Bb 16
#define Lq 2048
#define Hh 256
#define NLay 4
#define IND 40
#define OUTD 33

typedef unsigned int uint32;
typedef unsigned short ushort16;

typedef short bf16x8 __attribute__((ext_vector_type(8)));
typedef float f32x4 __attribute__((ext_vector_type(4)));

__device__ __forceinline__ float sigmoidf_(float x) {
    return 1.0f / (1.0f + __expf(-x));
}
__device__ __forceinline__ float gelu_(float x) {
    float x2 = x * x;
    float u = x * fmaf(0.0713548162726f, x2, 1.5957691216057308f);
    return x * sigmoidf_(u);
}
__device__ __forceinline__ float dot4acc(float4 a, float4 b, float acc) {
    acc = fmaf(a.x, b.x, acc); acc = fmaf(a.y, b.y, acc);
    acc = fmaf(a.z, b.z, acc); acc = fmaf(a.w, b.w, acc);
    return acc;
}
__device__ __forceinline__ unsigned short f2bf(float f) {
    uint32 u = __float_as_uint(f);
    return (unsigned short)((u + 0x7fffu + ((u >> 16) & 1u)) >> 16);
}
__device__ __forceinline__ float bf2f(unsigned short s) {
    return __uint_as_float(((uint32)s) << 16);
}
__device__ __forceinline__ void gload16(const void* g, void* l) {
    __builtin_amdgcn_global_load_lds(
        (const __attribute__((address_space(1))) unsigned int*)g,
        (__attribute__((address_space(3))) unsigned int*)l, 16, 0, 0);
}

// ---------------- encoder ----------------
__global__ __launch_bounds__(256) void enc_kernel(const float* __restrict__ x,
                                                  const float* __restrict__ enc_w,
                                                  const float* __restrict__ enc_b,
                                                  float* __restrict__ h) {
    __shared__ float xs[8 * IND];
    int tid = threadIdx.x;
    int t0 = blockIdx.x * 8;
    for (int i = tid; i < 8 * IND; i += 256) xs[i] = x[t0 * IND + i];
    float w[IND];
    const float4* w4 = (const float4*)(enc_w + tid * IND);
#pragma unroll
    for (int c = 0; c < 10; ++c) {
        float4 v = w4[c];
        w[4 * c] = v.x; w[4 * c + 1] = v.y; w[4 * c + 2] = v.z; w[4 * c + 3] = v.w;
    }
    float bias = enc_b[tid];
    __syncthreads();
#pragma unroll
    for (int t = 0; t < 8; ++t) {
        float acc = bias;
#pragma unroll
        for (int i = 0; i < IND; ++i) acc = fmaf(xs[t * IND + i], w[i], acc);
        h[(size_t)(t0 + t) * Hh + tid] = acc;
    }
}

// ---------------- weight fp32->bf16 conversion (per launch) ----------------
__global__ __launch_bounds__(256) void wconv_kernel(const float* __restrict__ w1,
                                                    const float* __restrict__ w2,
                                                    unsigned short* __restrict__ o) {
    int idx = blockIdx.x * 256 + threadIdx.x;   // 0..32767
    for (int i = idx; i < 65536; i += 32768) {  // 262144 floats per array / 4
        float4 a = ((const float4*)w1)[i];
        ushort4 u;
        u.x = f2bf(a.x); u.y = f2bf(a.y); u.z = f2bf(a.z); u.w = f2bf(a.w);
        ((ushort4*)o)[i] = u;
        float4 b4 = ((const float4*)w2)[i];
        ushort4 v;
        v.x = f2bf(b4.x); v.y = f2bf(b4.y); v.z = f2bf(b4.z); v.w = f2bf(b4.w);
        ((ushort4*)(o + 262144))[i] = v;
    }
}

// ---------------- layernorm + transpose: h[t][H] fp32 -> zT[b][h][t] bf16 ----------------
__global__ __launch_bounds__(256) void lnt_kernel(const float* __restrict__ h,
                                                  const float* __restrict__ scale,
                                                  const float* __restrict__ bias,
                                                  uint32* __restrict__ zT_u) {
    __shared__ float T[32 * 260];
    __shared__ float musab[64];   // mu[0..31], rs[32..63]
    __shared__ float scb[512];    // scale[0..255], bias[256..511]
    int tid = threadIdx.x, lane = tid & 63, wv = tid >> 6;
    size_t t0 = (size_t)blockIdx.x * 32;
    int b = (int)(t0 >> 11);
    int tloc = (int)(t0 & 2047);
    scb[tid] = scale[tid];
    scb[256 + tid] = bias[tid];
#pragma unroll
    for (int p = 0; p < 8; ++p) {
        int idx = tid + p * 256;
        int r = idx >> 6, c4 = idx & 63;
        float4 v = *(const float4*)&h[(t0 + r) * Hh + c4 * 4];
        *(float4*)&T[r * 260 + c4 * 4] = v;
    }
    __syncthreads();
    for (int tok = wv; tok < 32; tok += 4) {
        float4 v = *(const float4*)&T[tok * 260 + lane * 4];
        float s = (v.x + v.y) + (v.z + v.w);
        float q = fmaf(v.x, v.x, fmaf(v.y, v.y, fmaf(v.z, v.z, v.w * v.w)));
#pragma unroll
        for (int m = 1; m < 64; m <<= 1) {
            s += __shfl_xor(s, m, 64);
            q += __shfl_xor(q, m, 64);
        }
        if (lane == 0) {
            float mu = s * (1.0f / 256.0f);
            float var = q * (1.0f / 256.0f) - mu * mu;
            musab[tok] = mu;
            musab[32 + tok] = rsqrtf(var + 1e-5f);
        }
    }
    __syncthreads();
#pragma unroll
    for (int j = 0; j < 16; ++j) {
        int hh = wv * 64 + j * 4 + (lane >> 4);
        int tp = lane & 15;
        float v0 = T[(2 * tp) * 260 + hh];
        float v1 = T[(2 * tp + 1) * 260 + hh];
        float m0 = musab[2 * tp], r0 = musab[32 + 2 * tp];
        float m1 = musab[2 * tp + 1], r1 = musab[33 + 2 * tp];
        float sc = scb[hh], bi = scb[256 + hh];
        float o0 = fmaf((v0 - m0) * r0, sc, bi);
        float o1 = fmaf((v1 - m1) * r1, sc, bi);
        uint32 pk = ((uint32)f2bf(o1) << 16) | (uint32)f2bf(o0);
        zT_u[(size_t)(b * 256 + hh) * 1024 + (tloc >> 1) + tp] = pk;
    }
}

// ---------------- SSM scan: zT[b][h][t] bf16 -> yT[b][h][t] bf16 (gelu'd) ----------------
__global__ __launch_bounds__(256) void scan_kernel(const unsigned short* __restrict__ zT,
                                                   unsigned short* __restrict__ yT,
                                                   const float* __restrict__ lre_p,
                                                   const float* __restrict__ lim_p,
                                                   const float* __restrict__ cre_p,
                                                   const float* __restrict__ cim_p,
                                                   const float* __restrict__ d_p,
                                                   const float* __restrict__ ls_p) {
    __shared__ float pbuf[4][64][68];
    __shared__ float zbf[4][64];
    int lane = threadIdx.x & 63;
    int wid = threadIdx.x >> 6;
    int p = blockIdx.x;
    int lt = ((p & 7) << 7) | (p >> 3);   // XCD swizzle, bijective for 1024 blocks
    int w = lt * 4 + wid;
    int b = w >> 8;
    int hh = w & 255;

    int pidx = hh * 64 + lane;
    float lre = lre_p[pidx], lim = lim_p[pidx];
    float cre = cre_p[pidx], cim = cim_p[pidx];
    float dt = expf(ls_p[hh]);
    float dh = d_p[hh];
    float er = expf(lre * dt);
    float th = lim * dt;
    float dAre = er * cosf(th);
    float dAim = er * sinf(th);
    float inv = 1.0f / (lre * lre + lim * lim);
    float dBre = ((dAre - 1.0f) * lre + dAim * lim) * inv;
    float dBim = (dAim * lre - (dAre - 1.0f) * lim) * inv;
    float kr = 2.0f * (cre * dBre - cim * dBim);
    float ki = 2.0f * (cre * dBim + cim * dBre);

    // folded state w = c * s  (c = kr + i*ki):  w' = dA*w + c*z ; p = Re(w)
    float wre = 0.0f, wim = 0.0f;
    float(*pb)[68] = pbuf[wid];
    float* zb = zbf[wid];
    size_t base = (size_t)(b * 256 + hh) * 2048;

    for (int tt = 0; tt < Lq / 64; ++tt) {
        float zt = bf2f(zT[base + tt * 64 + lane]);
        zb[lane] = zt;
#pragma unroll
        for (int l = 0; l < 64; ++l) {
            float zl = zb[l];
            float kz = kr * zl;
            float kiz = ki * zl;
            float nre = fmaf(dAre, wre, fmaf(-dAim, wim, kz));
            float nim = fmaf(dAre, wim, fmaf(dAim, wre, kiz));
            wre = nre; wim = nim;
            pb[l][lane] = wre;
        }
        float acc = 0.0f;
        const float4* prow = (const float4*)pb[lane];
#pragma unroll
        for (int c = 0; c < 16; ++c) {
            float4 r = prow[c];
            acc += (r.x + r.y) + (r.z + r.w);
        }
        float y = fmaf(dh, zt, acc);
        yT[base + tt * 64 + lane] = f2bf(gelu_(y));
    }
}

// ---------------- transpose yT[b][h][t] bf16 -> yrow[tau][h] bf16 (u32/v_perm 2x2) ----------------
__global__ __launch_bounds__(256) void tpose_kernel(const uint32* __restrict__ yT_u,
                                                    uint32* __restrict__ yrow_u) {
    __shared__ uint32 S[64 * 40];
    int tid = threadIdx.x;
    int b = blockIdx.z;
    int h0 = blockIdx.y * 64;
    int tl0 = blockIdx.x * 64;
#pragma unroll
    for (int p = 0; p < 2; ++p) {
        int c = tid + p * 256;
        int hr = c >> 3, c4 = c & 7;
        const uint32* g = yT_u + (size_t)(b * 256 + h0 + hr) * 1024 + (tl0 >> 1) + c4 * 4;
        uint4 v = *(const uint4*)g;
        int col4 = c4 ^ ((hr >> 3) & 7);
        *(uint4*)&S[hr * 40 + col4 * 4] = v;
    }
    __syncthreads();
#pragma unroll
    for (int p = 0; p < 2; ++p) {
        int oc = tid + p * 256;
        int tr = oc >> 3, q8 = oc & 7;
        int tp = tr >> 1;
        uint32 sel = (tr & 1) ? 0x07060302u : 0x05040100u;
        uint4 o;
        uint32* op = (uint32*)&o;
#pragma unroll
        for (int q = 0; q < 4; ++q) {
            int hh = q8 * 8 + 2 * q;
            int c4a = (tp >> 2) ^ (q8 & 7);
            uint32 a = S[hh * 40 + c4a * 4 + (tp & 3)];
            uint32 bq = S[(hh + 1) * 40 + c4a * 4 + (tp & 3)];
            op[q] = __builtin_amdgcn_perm(bq, a, sel);
        }
        size_t tau = (size_t)b * 2048 + tl0 + tr;
        *(uint4*)&yrow_u[tau * 128 + (h0 >> 1) + q8 * 4] = o;
    }
}

// ---------------- gated MFMA GEMM + residual ----------------
// h[t][g] += (y@W1^T + b1) * sigmoid(y@W2^T + b2), y bf16 [32768][256], W bf16 [256][256]
__global__ __launch_bounds__(256, 2) void gated_kernel(const unsigned short* __restrict__ yrow,
                                                       const unsigned short* __restrict__ w1b,
                                                       const unsigned short* __restrict__ w2b,
                                                       const float* __restrict__ b1,
                                                       const float* __restrict__ b2,
                                                       float* __restrict__ h) {
    __shared__ unsigned short Al[128 * 32];
    __shared__ unsigned short W1l[128 * 32];
    __shared__ unsigned short W2l[128 * 32];
    int tid = threadIdx.x;
    int lane = tid & 63;
    int wv = tid >> 6;
    int wm = wv >> 1, wn = wv & 1;
    int lr = lane & 15, lg = lane >> 4;
    size_t t0 = (size_t)blockIdx.x * 128;
    int g0 = blockIdx.y * 128;

    f32x4 acc1[4][4], acc2[4][4];
    f32x4 zf = {0.f, 0.f, 0.f, 0.f};
#pragma unroll
    for (int i = 0; i < 4; ++i)
#pragma unroll
        for (int j = 0; j < 4; ++j) { acc1[i][j] = zf; acc2[i][j] = zf; }

    for (int kt = 0; kt < 8; ++kt) {
        __syncthreads();
        int k0 = kt * 32;
#pragma unroll
        for (int p = 0; p < 2; ++p) {
            int c = p * 256 + wv * 64 + lane;
            int row = c >> 2, q = c & 3;
            int ldsoff = (p * 256 + wv * 64) * 16;  // bytes, wave-uniform base
            gload16(yrow + (t0 + row) * 256 + k0 + q * 8, (char*)Al + ldsoff);
            gload16(w1b + (size_t)(g0 + row) * 256 + k0 + q * 8, (char*)W1l + ldsoff);
            gload16(w2b + (size_t)(g0 + row) * 256 + k0 + q * 8, (char*)W2l + ldsoff);
        }
        __syncthreads();
        bf16x8 a[4], f1[4], f2[4];
#pragma unroll
        for (int i = 0; i < 4; ++i)
            a[i] = *(const bf16x8*)(Al + (wm * 64 + i * 16 + lr) * 32 + lg * 8);
#pragma unroll
        for (int j = 0; j < 4; ++j) {
            f1[j] = *(const bf16x8*)(W1l + (wn * 64 + j * 16 + lr) * 32 + lg * 8);
            f2[j] = *(const bf16x8*)(W2l + (wn * 64 + j * 16 + lr) * 32 + lg * 8);
        }
#pragma unroll
        for (int i = 0; i < 4; ++i)
#pragma unroll
            for (int j = 0; j < 4; ++j) {
                acc1[i][j] = __builtin_amdgcn_mfma_f32_16x16x32_bf16(a[i], f1[j], acc1[i][j], 0, 0, 0);
                acc2[i][j] = __builtin_amdgcn_mfma_f32_16x16x32_bf16(a[i], f2[j], acc2[i][j], 0, 0, 0);
            }
    }

    float bb1[4], bb2[4];
#pragma unroll
    for (int j = 0; j < 4; ++j) {
        int g = g0 + wn * 64 + j * 16 + lr;
        bb1[j] = b1[g];
        bb2[j] = b2[g];
    }
#pragma unroll
    for (int i = 0; i < 4; ++i)
#pragma unroll
        for (int j = 0; j < 4; ++j) {
            int g = g0 + wn * 64 + j * 16 + lr;
#pragma unroll
            for (int r = 0; r < 4; ++r) {
                size_t t = t0 + wm * 64 + i * 16 + lg * 4 + r;
                float p1 = acc1[i][j][r] + bb1[j];
                float p2 = acc2[i][j][r] + bb2[j];
                float* hp = &h[t * Hh + g];
                *hp = fmaf(p1, sigmoidf_(p2), *hp);
            }
        }
}

// ---------------- decoder ----------------
__global__ __launch_bounds__(256) void dec_kernel(const float* __restrict__ h,
                                                  const float* __restrict__ dec_w,
                                                  const float* __restrict__ dec_b,
                                                  float* __restrict__ out) {
    __shared__ float wT[256][36];
    __shared__ float hs[64][20];
    int tid = threadIdx.x;
    for (int idx = tid; idx < OUTD * Hh; idx += 256) {
        int o = idx >> 8, k = idx & 255;
        wT[k][o] = dec_w[idx];
    }
    size_t t0 = (size_t)blockIdx.x * 64;
    int tl = tid & 63, og = tid >> 6;
    float acc[9];
#pragma unroll
    for (int j = 0; j < 9; ++j) acc[j] = 0.0f;
    int i = tid >> 2, c = (tid & 3) * 4;
    for (int kt = 0; kt < 16; ++kt) {
        __syncthreads();
        *(float4*)&hs[i][c] = *(const float4*)&h[(t0 + i) * Hh + kt * 16 + c];
        __syncthreads();
#pragma unroll
        for (int k2 = 0; k2 < 16; ++k2) {
            float a = hs[tl][k2];
            int kk = kt * 16 + k2;
#pragma unroll
            for (int j = 0; j < 9; ++j) acc[j] = fmaf(a, wT[kk][og + 4 * j], acc[j]);
        }
    }
#pragma unroll
    for (int j = 0; j < 9; ++j) {
        int o = og + 4 * j;
        if (o < OUTD) out[(t0 + tl) * OUTD + o] = acc[j] + dec_b[o];
    }
}

extern "C" void kernel_launch(void* const* d_in, const int* in_sizes, int n_in,
                              void* d_out, int out_size, void* d_ws, size_t ws_size,
                              hipStream_t stream) {
    const float* x = (const float*)d_in[0];
    const float* enc_w = (const float*)d_in[1];
    const float* enc_b = (const float*)d_in[2];
    const float* lre = (const float*)d_in[3];
    const float* lim = (const float*)d_in[4];
    const float* cre = (const float*)d_in[5];
    const float* cim = (const float*)d_in[6];
    const float* dd = (const float*)d_in[7];
    const float* ls = (const float*)d_in[8];
    const float* lns = (const float*)d_in[9];
    const float* lnb = (const float*)d_in[10];
    const float* w1 = (const float*)d_in[11];
    const float* b1 = (const float*)d_in[12];
    const float* w2 = (const float*)d_in[13];
    const float* b2 = (const float*)d_in[14];
    const float* dw = (const float*)d_in[15];
    const float* db = (const float*)d_in[16];
    float* out = (float*)d_out;

    const size_t NTOK = (size_t)Bb * Lq;        // 32768
    float* hbuf = (float*)d_ws;                 // 32MB fp32
    unsigned short* zT = (unsigned short*)(hbuf + NTOK * Hh);   // 16MB bf16 [b][h][t]
    unsigned short* yT = zT + NTOK * Hh;                        // 16MB bf16 [b][h][t]
    unsigned short* wbf = yT + NTOK * Hh;                       // 1MB bf16 weights
    unsigned short* yrow = zT;                  // reuse zT region after scan: [tau][h] bf16

    wconv_kernel<<<128, 256, 0, stream>>>(w1, w2, wbf);
    enc_kernel<<<(int)(NTOK / 8), 256, 0, stream>>>(x, enc_w, enc_b, hbuf);
    for (int il = 0; il < NLay; ++il) {
        lnt_kernel<<<(int)(NTOK / 32), 256, 0, stream>>>(hbuf, lns + il * Hh, lnb + il * Hh,
                                                         (uint32*)zT);
        scan_kernel<<<1024, 256, 0, stream>>>(zT, yT,
                                              lre + il * Hh * 64, lim + il * Hh * 64,
                                              cre + il * Hh * 64, cim + il * Hh * 64,
                                              dd + il * Hh, ls + il * Hh);
        tpose_kernel<<<dim3(32, 4, 16), 256, 0, stream>>>((const uint32*)yT, (uint32*)yrow);
        gated_kernel<<<dim3(256, 2), 256, 0, stream>>>(yrow,
                                                       wbf + il * 65536,
                                                       wbf + 262144 + il * 65536,
                                                       b1 + il * Hh, b2 + il * Hh, hbuf);
    }
    dec_kernel<<<(int)(NTOK / 64), 256, 0, stream>>>(hbuf, dw, db, out);
}

// Round 4
// 634.591 us; speedup vs baseline: 2.0890x; 1.3110x over previous
//
#include <hip/hip_runtime.h>
#include <hip/hip_bf16.h>

#define Bb 16
#define Lq 2048
#define Hh 256
#define NLay 4
#define IND 40
#define OUTD 33

typedef unsigned int uint32;
typedef unsigned short ushort_t;

typedef short bf16x8 __attribute__((ext_vector_type(8)));
typedef float f32x4 __attribute__((ext_vector_type(4)));

__device__ __forceinline__ float sigmoidf_(float x) {
    return 1.0f / (1.0f + __expf(-x));
}
__device__ __forceinline__ float gelu_(float x) {
    float x2 = x * x;
    float u = x * fmaf(0.0713548162726f, x2, 1.5957691216057308f);
    return x * sigmoidf_(u);
}
__device__ __forceinline__ unsigned short f2bf(float f) {
    uint32 u = __float_as_uint(f);
    return (unsigned short)((u + 0x7fffu + ((u >> 16) & 1u)) >> 16);
}
__device__ __forceinline__ float bf2f(unsigned short s) {
    return __uint_as_float(((uint32)s) << 16);
}
__device__ __forceinline__ void gload16(const void* g, void* l) {
    __builtin_amdgcn_global_load_lds(
        (const __attribute__((address_space(1))) unsigned int*)g,
        (__attribute__((address_space(3))) unsigned int*)l, 16, 0, 0);
}

// ---------------- encoder ----------------
__global__ __launch_bounds__(256) void enc_kernel(const float* __restrict__ x,
                                                  const float* __restrict__ enc_w,
                                                  const float* __restrict__ enc_b,
                                                  float* __restrict__ h) {
    __shared__ float xs[8 * IND];
    int tid = threadIdx.x;
    int t0 = blockIdx.x * 8;
    for (int i = tid; i < 8 * IND; i += 256) xs[i] = x[t0 * IND + i];
    float w[IND];
    const float4* w4 = (const float4*)(enc_w + tid * IND);
#pragma unroll
    for (int c = 0; c < 10; ++c) {
        float4 v = w4[c];
        w[4 * c] = v.x; w[4 * c + 1] = v.y; w[4 * c + 2] = v.z; w[4 * c + 3] = v.w;
    }
    float bias = enc_b[tid];
    __syncthreads();
#pragma unroll
    for (int t = 0; t < 8; ++t) {
        float acc = bias;
#pragma unroll
        for (int i = 0; i < IND; ++i) acc = fmaf(xs[t * IND + i], w[i], acc);
        h[(size_t)(t0 + t) * Hh + tid] = acc;
    }
}

// ---------------- weight fp32->bf16 conversion ----------------
__global__ __launch_bounds__(256) void wconv_kernel(const float* __restrict__ w1,
                                                    const float* __restrict__ w2,
                                                    unsigned short* __restrict__ o) {
    int idx = blockIdx.x * 256 + threadIdx.x;
    for (int i = idx; i < 65536; i += 32768) {
        float4 a = ((const float4*)w1)[i];
        ushort4 u;
        u.x = f2bf(a.x); u.y = f2bf(a.y); u.z = f2bf(a.z); u.w = f2bf(a.w);
        ((ushort4*)o)[i] = u;
        float4 b4 = ((const float4*)w2)[i];
        ushort4 v;
        v.x = f2bf(b4.x); v.y = f2bf(b4.y); v.z = f2bf(b4.z); v.w = f2bf(b4.w);
        ((ushort4*)(o + 262144))[i] = v;
    }
}

// ---------------- layernorm + transpose: h[t][H] fp32 -> zT[b][h][t] bf16 (chunk-swizzled) ----------------
__global__ __launch_bounds__(256) void lnt_kernel(const float* __restrict__ h,
                                                  const float* __restrict__ scale,
                                                  const float* __restrict__ bias,
                                                  uint32* __restrict__ zT_u) {
    __shared__ float T[32 * 260];
    __shared__ float musab[64];
    __shared__ float scb[512];
    int tid = threadIdx.x, lane = tid & 63, wv = tid >> 6;
    size_t t0 = (size_t)blockIdx.x * 32;
    int b = (int)(t0 >> 11);
    int tloc = (int)(t0 & 2047);
    scb[tid] = scale[tid];
    scb[256 + tid] = bias[tid];
#pragma unroll
    for (int p = 0; p < 8; ++p) {
        int idx = tid + p * 256;
        int r = idx >> 6, c4 = idx & 63;
        float4 v = *(const float4*)&h[(t0 + r) * Hh + c4 * 4];
        *(float4*)&T[r * 260 + c4 * 4] = v;
    }
    __syncthreads();
    for (int tok = wv; tok < 32; tok += 4) {
        float4 v = *(const float4*)&T[tok * 260 + lane * 4];
        float s = (v.x + v.y) + (v.z + v.w);
        float q = fmaf(v.x, v.x, fmaf(v.y, v.y, fmaf(v.z, v.z, v.w * v.w)));
#pragma unroll
        for (int m = 1; m < 64; m <<= 1) {
            s += __shfl_xor(s, m, 64);
            q += __shfl_xor(q, m, 64);
        }
        if (lane == 0) {
            float mu = s * (1.0f / 256.0f);
            float var = q * (1.0f / 256.0f) - mu * mu;
            musab[tok] = mu;
            musab[32 + tok] = rsqrtf(var + 1e-5f);
        }
    }
    __syncthreads();
#pragma unroll
    for (int j = 0; j < 16; ++j) {
        int hh = wv * 64 + j * 4 + (lane >> 4);
        int tp = lane & 15;
        float v0 = T[(2 * tp) * 260 + hh];
        float v1 = T[(2 * tp + 1) * 260 + hh];
        float m0 = musab[2 * tp], r0 = musab[32 + 2 * tp];
        float m1 = musab[2 * tp + 1], r1 = musab[33 + 2 * tp];
        float sc = scb[hh], bi = scb[256 + hh];
        float o0 = fmaf((v0 - m0) * r0, sc, bi);
        float o1 = fmaf((v1 - m1) * r1, sc, bi);
        uint32 pk = ((uint32)f2bf(o1) << 16) | (uint32)f2bf(o0);
        uint32 u = (uint32)((tloc >> 1) + tp);
        // bake ssm's LDS chunk swizzle: 16B chunk c within 64-token tile stored at c ^ (tile&7)
        uint32 usw = (u & ~28u) | ((((u >> 2) & 7u) ^ ((u >> 5) & 7u)) << 2);
        zT_u[(size_t)(b * 256 + hh) * 1024 + usw] = pk;
    }
}

// ---------------- k1: per-h chunked-scan matrices (pre-swizzled, SPLIT hi/lo bf16) ----------------
// tv[h] = [384][64]: 0..63 T_hi; 64..127 T_lo; 128..191 Vre_hi; 192..255 Vim_hi;
//                    256..319 Vre_lo; 320..383 Vim_lo
// eb[h] = [64][128]: E'(l,n)=2Re(dA^{l+1}), E'(l,64+n)=-2Im(dA^{l+1});  da64[h][2][64]
__global__ __launch_bounds__(256) void k1_kernel(const float* __restrict__ lre_p,
                                                 const float* __restrict__ lim_p,
                                                 const float* __restrict__ cre_p,
                                                 const float* __restrict__ cim_p,
                                                 const float* __restrict__ d_p,
                                                 const float* __restrict__ ls_p,
                                                 unsigned short* __restrict__ tv,
                                                 unsigned short* __restrict__ eb,
                                                 float* __restrict__ da64) {
    __shared__ float aa[64], tt[64], Gr[64], Gi[64], ks[64];
    int h = blockIdx.x;
    int tid = threadIdx.x;
    int lane = tid & 63, q = tid >> 6;
    if (tid < 64) {
        int n = tid;
        float lre = lre_p[h * 64 + n], lim = lim_p[h * 64 + n];
        float cre = cre_p[h * 64 + n], cim = cim_p[h * 64 + n];
        float dt = expf(ls_p[h]);
        float a = lre * dt, th = lim * dt;
        float er = expf(a);
        float s, c;
        sincosf(th, &s, &c);
        float dAre = er * c, dAim = er * s;
        float inv = 1.0f / (lre * lre + lim * lim);
        float dBre = ((dAre - 1.0f) * lre + dAim * lim) * inv;
        float dBim = (dAim * lre - (dAre - 1.0f) * lim) * inv;
        aa[n] = a; tt[n] = th;
        Gr[n] = cre * dBre - cim * dBim;
        Gi[n] = cre * dBim + cim * dBre;
    }
    __syncthreads();
    {
        float a = aa[lane], th = tt[lane], gr = Gr[lane], gi = Gi[lane];
        for (int mm = 0; mm < 16; ++mm) {
            int m = q * 16 + mm;
            float er = expf(m * a);
            float s, c;
            sincosf(m * th, &s, &c);
            float v = gr * (er * c) - gi * (er * s);
#pragma unroll
            for (int msk = 1; msk < 64; msk <<= 1) v += __shfl_xor(v, msk, 64);
            if (lane == 0) ks[m] = 2.0f * v;
        }
    }
    __syncthreads();
    float dh = d_p[h];
    size_t basep = (size_t)h * 24576;
#pragma unroll
    for (int i2 = 0; i2 < 16; ++i2) {   // T' hi + lo
        int e = tid + i2 * 256;
        int l = e >> 6, j = e & 63;
        float v = (j < l) ? ks[l - j] : (j == l ? ks[0] + dh : 0.0f);
        int sj = (((j >> 3) ^ (l & 7)) << 3) | (j & 7);
        unsigned short hi = f2bf(v);
        tv[basep + l * 64 + sj] = hi;
        tv[basep + (64 + l) * 64 + sj] = f2bf(v - bf2f(hi));
    }
#pragma unroll
    for (int i2 = 0; i2 < 32; ++i2) {   // V' hi + lo
        int e = tid + i2 * 256;
        int part = e >> 12, n = (e >> 6) & 63, j = e & 63;
        int m = 63 - j;
        float er = expf(m * aa[n]);
        float s, c;
        sincosf(m * tt[n], &s, &c);
        float pre = er * c, pim = er * s;
        float v = part ? (Gr[n] * pim + Gi[n] * pre) : (Gr[n] * pre - Gi[n] * pim);
        int sj = (((j >> 3) ^ (n & 7)) << 3) | (j & 7);
        unsigned short hi = f2bf(v);
        tv[basep + (size_t)(128 + part * 64 + n) * 64 + sj] = hi;
        tv[basep + (size_t)(256 + part * 64 + n) * 64 + sj] = f2bf(v - bf2f(hi));
    }
#pragma unroll
    for (int i2 = 0; i2 < 32; ++i2) {   // E'
        int e = tid + i2 * 256;
        int l = e >> 7, k = e & 127;
        int n = k & 63, m = l + 1;
        float er = expf(m * aa[n]);
        float s, c;
        sincosf(m * tt[n], &s, &c);
        float v = (k < 64) ? 2.0f * er * c : -2.0f * er * s;
        eb[(size_t)h * 8192 + l * 128 + ((((k >> 3) ^ (l & 7)) << 3) | (k & 7))] = f2bf(v);
    }
    if (tid < 64) {
        int n = tid;
        float er = expf(64.0f * aa[n]);
        float s, c;
        sincosf(64.0f * tt[n], &s, &c);
        da64[h * 128 + n] = er * c;
        da64[h * 128 + 64 + n] = er * s;
    }
}

// ---------------- fused SSM (chunked scan, MFMA, split-precision carry): zT -> yT ----------------
__global__ __launch_bounds__(256) void ssm_kernel(const unsigned short* __restrict__ zT,
                                                  const unsigned short* __restrict__ tv,
                                                  const unsigned short* __restrict__ eb,
                                                  const float* __restrict__ da64,
                                                  unsigned short* __restrict__ yT) {
    static __shared__ __align__(16) char LDSA[81920];
    ushort_t* Zl = (ushort_t*)LDSA;              // [128][64] Z -> later E [64][128]
    ushort_t* TVl = (ushort_t*)(LDSA + 16384);   // [384][64] T/V hi+lo (48KB)
    ushort_t* B2l = (ushort_t*)(LDSA + 16384);   // U/W hi [128][128] + lo [128][128] (64KB, overlays TV)
    ushort_t* YBl = (ushort_t*)(LDSA + 16384);   // [128][72] y bounce (overlays B2)
    const int ULO = 16384;                       // ushort offset of lo plane within B2l
    int tid = threadIdx.x;
    int lane = tid & 63, wv = tid >> 6;
    int lr = lane & 15, lg = lane >> 4;
    int h = blockIdx.x, mb = blockIdx.y;

    float ar = da64[h * 128 + lane];
    float ai = da64[h * 128 + 64 + lane];

    // stage Z (16KB) + TV (48KB), all linear (swizzle pre-baked in global)
#pragma unroll
    for (int it = 0; it < 4; ++it) {
        int c = it * 256 + tid;
        int r = c >> 3, s = c & 7;
        int b = mb * 4 + (r >> 5), tile = r & 31;
        size_t src = ((size_t)(b * 256 + h) << 11) + tile * 64 + s * 8;
        gload16(zT + src, (char*)Zl + (it * 256 + wv * 64) * 16);
    }
#pragma unroll
    for (int it = 0; it < 12; ++it) {
        size_t src = (size_t)h * 24576 + (size_t)(it * 256 + tid) * 8;
        gload16(tv + src, (char*)TVl + (it * 256 + wv * 64) * 16);
    }
    __syncthreads();

    // GEMM1: [Y1 | U] = Z @ [T | V]  with hi+lo planes folded into the same fp32 acc
    f32x4 y1[2][4], ua[2][8];
    f32x4 zf = {0.f, 0.f, 0.f, 0.f};
#pragma unroll
    for (int i = 0; i < 2; ++i) {
#pragma unroll
        for (int j = 0; j < 4; ++j) y1[i][j] = zf;
#pragma unroll
        for (int j = 0; j < 8; ++j) ua[i][j] = zf;
    }
#pragma unroll
    for (int kk = 0; kk < 2; ++kk) {
        int row0 = wv * 32 + lr;
        int row1 = row0 + 16;
        bf16x8 a0 = *(const bf16x8*)(Zl + row0 * 64 + (((kk * 4 + lg) ^ (row0 & 7)) << 3));
        bf16x8 a1 = *(const bf16x8*)(Zl + row1 * 64 + (((kk * 4 + lg) ^ (row1 & 7)) << 3));
#pragma unroll
        for (int j = 0; j < 24; ++j) {
            int rw = (j < 4) ? (j * 16 + lr)
                   : (j < 8) ? (64 + (j - 4) * 16 + lr)
                   : (j < 16) ? (128 + (j - 8) * 16 + lr)
                   : (256 + (j - 16) * 16 + lr);
            bf16x8 bfr = *(const bf16x8*)(TVl + rw * 64 + (((kk * 4 + lg) ^ (rw & 7)) << 3));
            if (j < 8) {
                y1[0][j & 3] = __builtin_amdgcn_mfma_f32_16x16x32_bf16(a0, bfr, y1[0][j & 3], 0, 0, 0);
                y1[1][j & 3] = __builtin_amdgcn_mfma_f32_16x16x32_bf16(a1, bfr, y1[1][j & 3], 0, 0, 0);
            } else {
                int jj = (j - 8) & 7;
                ua[0][jj] = __builtin_amdgcn_mfma_f32_16x16x32_bf16(a0, bfr, ua[0][jj], 0, 0, 0);
                ua[1][jj] = __builtin_amdgcn_mfma_f32_16x16x32_bf16(a1, bfr, ua[1][jj], 0, 0, 0);
            }
        }
    }
    __syncthreads();   // all waves done reading Z & TV

    // stage E into Zl (overlap with U write-out)
#pragma unroll
    for (int it = 0; it < 4; ++it) {
        size_t src = (size_t)h * 8192 + (size_t)(it * 256 + tid) * 8;
        gload16(eb + src, (char*)Zl + (it * 256 + wv * 64) * 16);
    }
    // write U -> B2 (hi+lo bf16, chunk-swizzled)
#pragma unroll
    for (int i = 0; i < 2; ++i)
#pragma unroll
        for (int jj = 0; jj < 8; ++jj)
#pragma unroll
            for (int r = 0; r < 4; ++r) {
                int row = wv * 32 + i * 16 + lg * 4 + r;
                int col = (jj < 4) ? (jj * 16 + lr) : (64 + (jj - 4) * 16 + lr);
                int addr = row * 128 + ((((col >> 3) ^ (row & 7)) << 3) | (col & 7));
                float v = ua[i][jj][r];
                unsigned short hi = f2bf(v);
                B2l[addr] = hi;
                B2l[ULO + addr] = f2bf(v - bf2f(hi));
            }
    __syncthreads();   // U visible; E arrived (vmcnt drained at barrier)

    // carry scan (in place, fp32 via hi+lo): thread (wv=b_loc, lane=n)
    {
        float Sre = 0.0f, Sim = 0.0f;
#pragma unroll 4
        for (int r = 0; r < 32; ++r) {
            int row = wv * 32 + r;
            int x7 = row & 7;
            int aRe = row * 128 + ((((lane >> 3) ^ x7) << 3) | (lane & 7));
            int c2 = 64 + lane;
            int aIm = row * 128 + ((((c2 >> 3) ^ x7) << 3) | (c2 & 7));
            float ur = bf2f(B2l[aRe]) + bf2f(B2l[ULO + aRe]);
            float ui = bf2f(B2l[aIm]) + bf2f(B2l[ULO + aIm]);
            unsigned short h1 = f2bf(Sre);
            B2l[aRe] = h1;
            B2l[ULO + aRe] = f2bf(Sre - bf2f(h1));
            unsigned short h2 = f2bf(Sim);
            B2l[aIm] = h2;
            B2l[ULO + aIm] = f2bf(Sim - bf2f(h2));
            float nr = fmaf(ar, Sre, fmaf(-ai, Sim, ur));
            float ni = fmaf(ar, Sim, fmaf(ai, Sre, ui));
            Sre = nr; Sim = ni;
        }
    }
    __syncthreads();

    // GEMM2: Y2 = (W_hi + W_lo) @ E'
    f32x4 y2[2][4];
#pragma unroll
    for (int i = 0; i < 2; ++i)
#pragma unroll
        for (int j = 0; j < 4; ++j) y2[i][j] = zf;
#pragma unroll
    for (int kk = 0; kk < 4; ++kk) {
        int row0 = wv * 32 + lr;
        int row1 = row0 + 16;
        int s0 = (((kk * 4 + lg) ^ (row0 & 7)) << 3);
        int s1 = (((kk * 4 + lg) ^ (row1 & 7)) << 3);
        bf16x8 a0h = *(const bf16x8*)(B2l + row0 * 128 + s0);
        bf16x8 a0l = *(const bf16x8*)(B2l + ULO + row0 * 128 + s0);
        bf16x8 a1h = *(const bf16x8*)(B2l + row1 * 128 + s1);
        bf16x8 a1l = *(const bf16x8*)(B2l + ULO + row1 * 128 + s1);
#pragma unroll
        for (int j = 0; j < 4; ++j) {
            int rw = j * 16 + lr;
            bf16x8 bfr = *(const bf16x8*)(Zl + rw * 128 + (((kk * 4 + lg) ^ (rw & 7)) << 3));
            y2[0][j] = __builtin_amdgcn_mfma_f32_16x16x32_bf16(a0h, bfr, y2[0][j], 0, 0, 0);
            y2[0][j] = __builtin_amdgcn_mfma_f32_16x16x32_bf16(a0l, bfr, y2[0][j], 0, 0, 0);
            y2[1][j] = __builtin_amdgcn_mfma_f32_16x16x32_bf16(a1h, bfr, y2[1][j], 0, 0, 0);
            y2[1][j] = __builtin_amdgcn_mfma_f32_16x16x32_bf16(a1l, bfr, y2[1][j], 0, 0, 0);
        }
    }
    __syncthreads();   // done reading B2/E before YB overwrite

    // epilogue: y = gelu(Y1 + Y2) -> bounce
#pragma unroll
    for (int i = 0; i < 2; ++i)
#pragma unroll
        for (int j = 0; j < 4; ++j)
#pragma unroll
            for (int r = 0; r < 4; ++r) {
                int row = wv * 32 + i * 16 + lg * 4 + r;
                int col = j * 16 + lr;
                float y = y1[i][j][r] + y2[i][j][r];
                YBl[row * 72 + col] = f2bf(gelu_(y));
            }
    __syncthreads();

    // coalesced flush to yT [b][h][t] (linear, unswizzled)
#pragma unroll
    for (int it = 0; it < 4; ++it) {
        int c = it * 256 + tid;
        int row = c >> 3, c8 = c & 7;
        int b = mb * 4 + (row >> 5), tile = row & 31;
        uint4 v = *(const uint4*)((const char*)YBl + row * 144 + c8 * 16);
        *(uint4*)(yT + (((size_t)(b * 256 + h)) << 11) + tile * 64 + c8 * 8) = v;
    }
}

// ---------------- transpose yT[b][h][t] bf16 -> yrow[tau][h] bf16 ----------------
__global__ __launch_bounds__(256) void tpose_kernel(const uint32* __restrict__ yT_u,
                                                    uint32* __restrict__ yrow_u) {
    __shared__ uint32 S[64 * 40];
    int tid = threadIdx.x;
    int b = blockIdx.z;
    int h0 = blockIdx.y * 64;
    int tl0 = blockIdx.x * 64;
#pragma unroll
    for (int p = 0; p < 2; ++p) {
        int c = tid + p * 256;
        int hr = c >> 3, c4 = c & 7;
        const uint32* g = yT_u + (size_t)(b * 256 + h0 + hr) * 1024 + (tl0 >> 1) + c4 * 4;
        uint4 v = *(const uint4*)g;
        int col4 = c4 ^ ((hr >> 3) & 7);
        *(uint4*)&S[hr * 40 + col4 * 4] = v;
    }
    __syncthreads();
#pragma unroll
    for (int p = 0; p < 2; ++p) {
        int oc = tid + p * 256;
        int tr = oc >> 3, q8 = oc & 7;
        int tp = tr >> 1;
        uint32 sel = (tr & 1) ? 0x07060302u : 0x05040100u;
        uint4 o;
        uint32* op = (uint32*)&o;
#pragma unroll
        for (int q = 0; q < 4; ++q) {
            int hh = q8 * 8 + 2 * q;
            int c4a = (tp >> 2) ^ (q8 & 7);
            uint32 a = S[hh * 40 + c4a * 4 + (tp & 3)];
            uint32 bq = S[(hh + 1) * 40 + c4a * 4 + (tp & 3)];
            op[q] = __builtin_amdgcn_perm(bq, a, sel);
        }
        size_t tau = (size_t)b * 2048 + tl0 + tr;
        *(uint4*)&yrow_u[tau * 128 + (h0 >> 1) + q8 * 4] = o;
    }
}

// ---------------- gated MFMA GEMM + residual ----------------
__global__ __launch_bounds__(256, 2) void gated_kernel(const unsigned short* __restrict__ yrow,
                                                       const unsigned short* __restrict__ w1b,
                                                       const unsigned short* __restrict__ w2b,
                                                       const float* __restrict__ b1,
                                                       const float* __restrict__ b2,
                                                       float* __restrict__ h) {
    __shared__ unsigned short Al[128 * 32];
    __shared__ unsigned short W1l[128 * 32];
    __shared__ unsigned short W2l[128 * 32];
    int tid = threadIdx.x;
    int lane = tid & 63;
    int wv = tid >> 6;
    int wm = wv >> 1, wn = wv & 1;
    int lr = lane & 15, lg = lane >> 4;
    size_t t0 = (size_t)blockIdx.x * 128;
    int g0 = blockIdx.y * 128;

    f32x4 acc1[4][4], acc2[4][4];
    f32x4 zf = {0.f, 0.f, 0.f, 0.f};
#pragma unroll
    for (int i = 0; i < 4; ++i)
#pragma unroll
        for (int j = 0; j < 4; ++j) { acc1[i][j] = zf; acc2[i][j] = zf; }

    for (int kt = 0; kt < 8; ++kt) {
        __syncthreads();
        int k0 = kt * 32;
#pragma unroll
        for (int p = 0; p < 2; ++p) {
            int c = p * 256 + wv * 64 + lane;
            int row = c >> 2, q = c & 3;
            int ldsoff = (p * 256 + wv * 64) * 16;
            gload16(yrow + (t0 + row) * 256 + k0 + q * 8, (char*)Al + ldsoff);
            gload16(w1b + (size_t)(g0 + row) * 256 + k0 + q * 8, (char*)W1l + ldsoff);
            gload16(w2b + (size_t)(g0 + row) * 256 + k0 + q * 8, (char*)W2l + ldsoff);
        }
        __syncthreads();
        bf16x8 a[4], f1[4], f2[4];
#pragma unroll
        for (int i = 0; i < 4; ++i)
            a[i] = *(const bf16x8*)(Al + (wm * 64 + i * 16 + lr) * 32 + lg * 8);
#pragma unroll
        for (int j = 0; j < 4; ++j) {
            f1[j] = *(const bf16x8*)(W1l + (wn * 64 + j * 16 + lr) * 32 + lg * 8);
            f2[j] = *(const bf16x8*)(W2l + (wn * 64 + j * 16 + lr) * 32 + lg * 8);
        }
#pragma unroll
        for (int i = 0; i < 4; ++i)
#pragma unroll
            for (int j = 0; j < 4; ++j) {
                acc1[i][j] = __builtin_amdgcn_mfma_f32_16x16x32_bf16(a[i], f1[j], acc1[i][j], 0, 0, 0);
                acc2[i][j] = __builtin_amdgcn_mfma_f32_16x16x32_bf16(a[i], f2[j], acc2[i][j], 0, 0, 0);
            }
    }

    float bb1[4], bb2[4];
#pragma unroll
    for (int j = 0; j < 4; ++j) {
        int g = g0 + wn * 64 + j * 16 + lr;
        bb1[j] = b1[g];
        bb2[j] = b2[g];
    }
#pragma unroll
    for (int i = 0; i < 4; ++i)
#pragma unroll
        for (int j = 0; j < 4; ++j) {
            int g = g0 + wn * 64 + j * 16 + lr;
#pragma unroll
            for (int r = 0; r < 4; ++r) {
                size_t t = t0 + wm * 64 + i * 16 + lg * 4 + r;
                float p1 = acc1[i][j][r] + bb1[j];
                float p2 = acc2[i][j][r] + bb2[j];
                float* hp = &h[t * Hh + g];
                *hp = fmaf(p1, sigmoidf_(p2), *hp);
            }
        }
}

// ---------------- decoder ----------------
__global__ __launch_bounds__(256) void dec_kernel(const float* __restrict__ h,
                                                  const float* __restrict__ dec_w,
                                                  const float* __restrict__ dec_b,
                                                  float* __restrict__ out) {
    __shared__ float wT[256][36];
    __shared__ float hs[64][20];
    int tid = threadIdx.x;
    for (int idx = tid; idx < OUTD * Hh; idx += 256) {
        int o = idx >> 8, k = idx & 255;
        wT[k][o] = dec_w[idx];
    }
    size_t t0 = (size_t)blockIdx.x * 64;
    int tl = tid & 63, og = tid >> 6;
    float acc[9];
#pragma unroll
    for (int j = 0; j < 9; ++j) acc[j] = 0.0f;
    int i = tid >> 2, c = (tid & 3) * 4;
    for (int kt = 0; kt < 16; ++kt) {
        __syncthreads();
        *(float4*)&hs[i][c] = *(const float4*)&h[(t0 + i) * Hh + kt * 16 + c];
        __syncthreads();
#pragma unroll
        for (int k2 = 0; k2 < 16; ++k2) {
            float a = hs[tl][k2];
            int kk = kt * 16 + k2;
#pragma unroll
            for (int j = 0; j < 9; ++j) acc[j] = fmaf(a, wT[kk][og + 4 * j], acc[j]);
        }
    }
#pragma unroll
    for (int j = 0; j < 9; ++j) {
        int o = og + 4 * j;
        if (o < OUTD) out[(t0 + tl) * OUTD + o] = acc[j] + dec_b[o];
    }
}

extern "C" void kernel_launch(void* const* d_in, const int* in_sizes, int n_in,
                              void* d_out, int out_size, void* d_ws, size_t ws_size,
                              hipStream_t stream) {
    const float* x = (const float*)d_in[0];
    const float* enc_w = (const float*)d_in[1];
    const float* enc_b = (const float*)d_in[2];
    const float* lre = (const float*)d_in[3];
    const float* lim = (const float*)d_in[4];
    const float* cre = (const float*)d_in[5];
    const float* cim = (const float*)d_in[6];
    const float* dd = (const float*)d_in[7];
    const float* ls = (const float*)d_in[8];
    const float* lns = (const float*)d_in[9];
    const float* lnb = (const float*)d_in[10];
    const float* w1 = (const float*)d_in[11];
    const float* b1 = (const float*)d_in[12];
    const float* w2 = (const float*)d_in[13];
    const float* b2 = (const float*)d_in[14];
    const float* dw = (const float*)d_in[15];
    const float* db = (const float*)d_in[16];
    float* out = (float*)d_out;

    const size_t NTOK = (size_t)Bb * Lq;
    float* hbuf = (float*)d_ws;                                   // 32MB fp32
    unsigned short* zT = (unsigned short*)(hbuf + NTOK * Hh);     // 16MB bf16 [b][h][t] (swizzled chunks)
    unsigned short* yT = zT + NTOK * Hh;                          // 16MB bf16 [b][h][t]
    unsigned short* wbf = yT + NTOK * Hh;                         // 1MB bf16 gated weights
    unsigned short* tv_slab = wbf + 524288;                       // 256*24576 bf16 = 12.6MB
    unsigned short* eb_slab = tv_slab + 6291456;                  // 256*8192 bf16 = 4.2MB
    float* da64 = (float*)(eb_slab + 2097152);                    // 256*128 f32
    unsigned short* yrow = zT;                                    // reuse zT region after ssm

    wconv_kernel<<<128, 256, 0, stream>>>(w1, w2, wbf);
    enc_kernel<<<(int)(NTOK / 8), 256, 0, stream>>>(x, enc_w, enc_b, hbuf);
    for (int il = 0; il < NLay; ++il) {
        k1_kernel<<<256, 256, 0, stream>>>(lre + il * 16384, lim + il * 16384,
                                           cre + il * 16384, cim + il * 16384,
                                           dd + il * Hh, ls + il * Hh,
                                           tv_slab, eb_slab, da64);
        lnt_kernel<<<(int)(NTOK / 32), 256, 0, stream>>>(hbuf, lns + il * Hh, lnb + il * Hh,
                                                         (uint32*)zT);
        ssm_kernel<<<dim3(256, 4), 256, 0, stream>>>(zT, tv_slab, eb_slab, da64, yT);
        tpose_kernel<<<dim3(32, 4, 16), 256, 0, stream>>>((const uint32*)yT, (uint32*)yrow);
        gated_kernel<<<dim3(256, 2), 256, 0, stream>>>(yrow,
                                                       wbf + il * 65536,
                                                       wbf + 262144 + il * 65536,
                                                       b1 + il * Hh, b2 + il * Hh, hbuf);
    }
    dec_kernel<<<(int)(NTOK / 64), 256, 0, stream>>>(hbuf, dw, db, out);
}

// Round 5
// 589.143 us; speedup vs baseline: 2.2501x; 1.0771x over previous
//
#include <hip/hip_runtime.h>
#include <hip/hip_bf16.h>

#define Bb 16
#define Lq 2048
#define Hh 256
#define NLay 4
#define IND 40
#define OUTD 33

typedef unsigned int uint32;
typedef unsigned short ushort_t;

typedef short bf16x8 __attribute__((ext_vector_type(8)));
typedef float f32x4 __attribute__((ext_vector_type(4)));

__device__ __forceinline__ float sigmoidf_(float x) {
    return 1.0f / (1.0f + __expf(-x));
}
__device__ __forceinline__ float gelu_(float x) {
    float x2 = x * x;
    float u = x * fmaf(0.0713548162726f, x2, 1.5957691216057308f);
    return x * sigmoidf_(u);
}
__device__ __forceinline__ unsigned short f2bf(float f) {
    uint32 u = __float_as_uint(f);
    return (unsigned short)((u + 0x7fffu + ((u >> 16) & 1u)) >> 16);
}
__device__ __forceinline__ float bf2f(unsigned short s) {
    return __uint_as_float(((uint32)s) << 16);
}
__device__ __forceinline__ void gload16(const void* g, void* l) {
    __builtin_amdgcn_global_load_lds(
        (const __attribute__((address_space(1))) unsigned int*)g,
        (__attribute__((address_space(3))) unsigned int*)l, 16, 0, 0);
}

// ---------------- encoder ----------------
__global__ __launch_bounds__(256) void enc_kernel(const float* __restrict__ x,
                                                  const float* __restrict__ enc_w,
                                                  const float* __restrict__ enc_b,
                                                  float* __restrict__ h) {
    __shared__ float xs[8 * IND];
    int tid = threadIdx.x;
    int t0 = blockIdx.x * 8;
    for (int i = tid; i < 8 * IND; i += 256) xs[i] = x[t0 * IND + i];
    float w[IND];
    const float4* w4 = (const float4*)(enc_w + tid * IND);
#pragma unroll
    for (int c = 0; c < 10; ++c) {
        float4 v = w4[c];
        w[4 * c] = v.x; w[4 * c + 1] = v.y; w[4 * c + 2] = v.z; w[4 * c + 3] = v.w;
    }
    float bias = enc_b[tid];
    __syncthreads();
#pragma unroll
    for (int t = 0; t < 8; ++t) {
        float acc = bias;
#pragma unroll
        for (int i = 0; i < IND; ++i) acc = fmaf(xs[t * IND + i], w[i], acc);
        h[(size_t)(t0 + t) * Hh + tid] = acc;
    }
}

// ---------------- weight fp32->bf16 conversion ----------------
__global__ __launch_bounds__(256) void wconv_kernel(const float* __restrict__ w1,
                                                    const float* __restrict__ w2,
                                                    unsigned short* __restrict__ o) {
    int idx = blockIdx.x * 256 + threadIdx.x;
    for (int i = idx; i < 65536; i += 32768) {
        float4 a = ((const float4*)w1)[i];
        ushort4 u;
        u.x = f2bf(a.x); u.y = f2bf(a.y); u.z = f2bf(a.z); u.w = f2bf(a.w);
        ((ushort4*)o)[i] = u;
        float4 b4 = ((const float4*)w2)[i];
        ushort4 v;
        v.x = f2bf(b4.x); v.y = f2bf(b4.y); v.z = f2bf(b4.z); v.w = f2bf(b4.w);
        ((ushort4*)(o + 262144))[i] = v;
    }
}

// ---------------- layernorm + transpose: h[t][H] fp32 -> zT[b][h][t] bf16 (chunk-swizzled) ----------------
__global__ __launch_bounds__(256) void lnt_kernel(const float* __restrict__ h,
                                                  const float* __restrict__ scale,
                                                  const float* __restrict__ bias,
                                                  uint32* __restrict__ zT_u) {
    __shared__ float T[32 * 260];
    __shared__ float musab[64];
    __shared__ float scb[512];
    int tid = threadIdx.x, lane = tid & 63, wv = tid >> 6;
    size_t t0 = (size_t)blockIdx.x * 32;
    int b = (int)(t0 >> 11);
    int tloc = (int)(t0 & 2047);
    scb[tid] = scale[tid];
    scb[256 + tid] = bias[tid];
#pragma unroll
    for (int p = 0; p < 8; ++p) {
        int idx = tid + p * 256;
        int r = idx >> 6, c4 = idx & 63;
        float4 v = *(const float4*)&h[(t0 + r) * Hh + c4 * 4];
        *(float4*)&T[r * 260 + c4 * 4] = v;
    }
    __syncthreads();
    for (int tok = wv; tok < 32; tok += 4) {
        float4 v = *(const float4*)&T[tok * 260 + lane * 4];
        float s = (v.x + v.y) + (v.z + v.w);
        float q = fmaf(v.x, v.x, fmaf(v.y, v.y, fmaf(v.z, v.z, v.w * v.w)));
#pragma unroll
        for (int m = 1; m < 64; m <<= 1) {
            s += __shfl_xor(s, m, 64);
            q += __shfl_xor(q, m, 64);
        }
        if (lane == 0) {
            float mu = s * (1.0f / 256.0f);
            float var = q * (1.0f / 256.0f) - mu * mu;
            musab[tok] = mu;
            musab[32 + tok] = rsqrtf(var + 1e-5f);
        }
    }
    __syncthreads();
#pragma unroll
    for (int j = 0; j < 16; ++j) {
        int hh = wv * 64 + j * 4 + (lane >> 4);
        int tp = lane & 15;
        float v0 = T[(2 * tp) * 260 + hh];
        float v1 = T[(2 * tp + 1) * 260 + hh];
        float m0 = musab[2 * tp], r0 = musab[32 + 2 * tp];
        float m1 = musab[2 * tp + 1], r1 = musab[33 + 2 * tp];
        float sc = scb[hh], bi = scb[256 + hh];
        float o0 = fmaf((v0 - m0) * r0, sc, bi);
        float o1 = fmaf((v1 - m1) * r1, sc, bi);
        uint32 pk = ((uint32)f2bf(o1) << 16) | (uint32)f2bf(o0);
        uint32 u = (uint32)((tloc >> 1) + tp);
        // bake ssm's LDS chunk swizzle: 16B chunk c within 64-token tile stored at c ^ (tile&7)
        uint32 usw = (u & ~28u) | ((((u >> 2) & 7u) ^ ((u >> 5) & 7u)) << 2);
        zT_u[(size_t)(b * 256 + hh) * 1024 + usw] = pk;
    }
}

// ---------------- k1: per-h chunked-scan matrices (pre-swizzled, SPLIT hi/lo bf16) ----------------
// tv[h] = [384][64]: 0..63 T_hi; 64..127 T_lo; 128..191 Vre_hi; 192..255 Vim_hi;
//                    256..319 Vre_lo; 320..383 Vim_lo
// eb[h] = [64][128]: E'(l,n)=2Re(dA^{l+1}), E'(l,64+n)=-2Im(dA^{l+1});  da64[h][2][64]
__global__ __launch_bounds__(256) void k1_kernel(const float* __restrict__ lre_p,
                                                 const float* __restrict__ lim_p,
                                                 const float* __restrict__ cre_p,
                                                 const float* __restrict__ cim_p,
                                                 const float* __restrict__ d_p,
                                                 const float* __restrict__ ls_p,
                                                 unsigned short* __restrict__ tv,
                                                 unsigned short* __restrict__ eb,
                                                 float* __restrict__ da64) {
    __shared__ float aa[64], tt[64], Gr[64], Gi[64], ks[64];
    int h = blockIdx.x;
    int tid = threadIdx.x;
    int lane = tid & 63, q = tid >> 6;
    if (tid < 64) {
        int n = tid;
        float lre = lre_p[h * 64 + n], lim = lim_p[h * 64 + n];
        float cre = cre_p[h * 64 + n], cim = cim_p[h * 64 + n];
        float dt = expf(ls_p[h]);
        float a = lre * dt, th = lim * dt;
        float er = expf(a);
        float s, c;
        sincosf(th, &s, &c);
        float dAre = er * c, dAim = er * s;
        float inv = 1.0f / (lre * lre + lim * lim);
        float dBre = ((dAre - 1.0f) * lre + dAim * lim) * inv;
        float dBim = (dAim * lre - (dAre - 1.0f) * lim) * inv;
        aa[n] = a; tt[n] = th;
        Gr[n] = cre * dBre - cim * dBim;
        Gi[n] = cre * dBim + cim * dBre;
    }
    __syncthreads();
    {
        float a = aa[lane], th = tt[lane], gr = Gr[lane], gi = Gi[lane];
        for (int mm = 0; mm < 16; ++mm) {
            int m = q * 16 + mm;
            float er = expf(m * a);
            float s, c;
            sincosf(m * th, &s, &c);
            float v = gr * (er * c) - gi * (er * s);
#pragma unroll
            for (int msk = 1; msk < 64; msk <<= 1) v += __shfl_xor(v, msk, 64);
            if (lane == 0) ks[m] = 2.0f * v;
        }
    }
    __syncthreads();
    float dh = d_p[h];
    size_t basep = (size_t)h * 24576;
#pragma unroll
    for (int i2 = 0; i2 < 16; ++i2) {   // T' hi + lo
        int e = tid + i2 * 256;
        int l = e >> 6, j = e & 63;
        float v = (j < l) ? ks[l - j] : (j == l ? ks[0] + dh : 0.0f);
        int sj = (((j >> 3) ^ (l & 7)) << 3) | (j & 7);
        unsigned short hi = f2bf(v);
        tv[basep + l * 64 + sj] = hi;
        tv[basep + (64 + l) * 64 + sj] = f2bf(v - bf2f(hi));
    }
#pragma unroll
    for (int i2 = 0; i2 < 32; ++i2) {   // V' hi + lo
        int e = tid + i2 * 256;
        int part = e >> 12, n = (e >> 6) & 63, j = e & 63;
        int m = 63 - j;
        float er = expf(m * aa[n]);
        float s, c;
        sincosf(m * tt[n], &s, &c);
        float pre = er * c, pim = er * s;
        float v = part ? (Gr[n] * pim + Gi[n] * pre) : (Gr[n] * pre - Gi[n] * pim);
        int sj = (((j >> 3) ^ (n & 7)) << 3) | (j & 7);
        unsigned short hi = f2bf(v);
        tv[basep + (size_t)(128 + part * 64 + n) * 64 + sj] = hi;
        tv[basep + (size_t)(256 + part * 64 + n) * 64 + sj] = f2bf(v - bf2f(hi));
    }
#pragma unroll
    for (int i2 = 0; i2 < 32; ++i2) {   // E'
        int e = tid + i2 * 256;
        int l = e >> 7, k = e & 127;
        int n = k & 63, m = l + 1;
        float er = expf(m * aa[n]);
        float s, c;
        sincosf(m * tt[n], &s, &c);
        float v = (k < 64) ? 2.0f * er * c : -2.0f * er * s;
        eb[(size_t)h * 8192 + l * 128 + ((((k >> 3) ^ (l & 7)) << 3) | (k & 7))] = f2bf(v);
    }
    if (tid < 64) {
        int n = tid;
        float er = expf(64.0f * aa[n]);
        float s, c;
        sincosf(64.0f * tt[n], &s, &c);
        da64[h * 128 + n] = er * c;
        da64[h * 128 + 64 + n] = er * s;
    }
}

// ---------------- fused SSM (chunked scan, MFMA, 48KB LDS, per-wave f32 scratch): zT -> yT ----------------
// Regions: R0=[0,16K): Z -> E ; R1=[16K,32K): T -> V_lo -> scratch(w0,w1) / YB
//          R2=[32K,48K): V_hi -> scratch(w2,w3) / YB tail
__global__ __launch_bounds__(256, 3) void ssm_kernel(const unsigned short* __restrict__ zT,
                                                     const unsigned short* __restrict__ tv,
                                                     const unsigned short* __restrict__ eb,
                                                     const float* __restrict__ da64,
                                                     unsigned short* __restrict__ yT) {
    static __shared__ __align__(16) char LDSA[49152];
    ushort_t* Zl = (ushort_t*)LDSA;              // [128][64] Z -> later E [64][128]
    ushort_t* R1 = (ushort_t*)(LDSA + 16384);    // T [128][64] -> V_lo [128][64]
    ushort_t* R2 = (ushort_t*)(LDSA + 32768);    // V_hi [128][64]
    ushort_t* YBl = (ushort_t*)(LDSA + 16384);   // [128][72] y bounce (post-scratch)
    int tid = threadIdx.x;
    int lane = tid & 63, wv = tid >> 6;
    int lr = lane & 15, lg = lane >> 4;
    int h = blockIdx.x, mb = blockIdx.y;

    float ar = da64[h * 128 + lane];
    float ai = da64[h * 128 + 64 + lane];

    // ---- stage Z (16KB), T (16KB), V_hi (16KB) ----
#pragma unroll
    for (int it = 0; it < 4; ++it) {
        int c = it * 256 + tid;
        int r = c >> 3, s = c & 7;
        int b = mb * 4 + (r >> 5), tile = r & 31;
        size_t src = ((size_t)(b * 256 + h) << 11) + tile * 64 + s * 8;
        gload16(zT + src, (char*)Zl + (it * 256 + wv * 64) * 16);
    }
#pragma unroll
    for (int it = 0; it < 4; ++it) {    // T rows 0..127
        size_t src = (size_t)h * 24576 + (size_t)(it * 256 + tid) * 8;
        gload16(tv + src, (char*)R1 + (it * 256 + wv * 64) * 16);
    }
#pragma unroll
    for (int it = 0; it < 4; ++it) {    // V_hi = tv rows 128..255
        size_t src = (size_t)h * 24576 + 8192 + (size_t)(it * 256 + tid) * 8;
        gload16(tv + src, (char*)R2 + (it * 256 + wv * 64) * 16);
    }
    __syncthreads();   // B1

    // ---- A-fragments of Z (held in regs for GEMM1 hi+lo phases) ----
    bf16x8 afz[2][2];  // [kk][rowblock]
#pragma unroll
    for (int kk = 0; kk < 2; ++kk) {
        int row0 = wv * 32 + lr;
        int row1 = row0 + 16;
        afz[kk][0] = *(const bf16x8*)(Zl + row0 * 64 + (((kk * 4 + lg) ^ (row0 & 7)) << 3));
        afz[kk][1] = *(const bf16x8*)(Zl + row1 * 64 + (((kk * 4 + lg) ^ (row1 & 7)) << 3));
    }

    f32x4 y1[2][4], ua[2][8];
    f32x4 zf = {0.f, 0.f, 0.f, 0.f};
#pragma unroll
    for (int i = 0; i < 2; ++i) {
#pragma unroll
        for (int j = 0; j < 4; ++j) y1[i][j] = zf;
#pragma unroll
        for (int j = 0; j < 8; ++j) ua[i][j] = zf;
    }

    // ---- GEMM1a: Y1 = Z@(T_hi+T_lo);  U += Z@V_hi ----
#pragma unroll
    for (int kk = 0; kk < 2; ++kk) {
#pragma unroll
        for (int j = 0; j < 8; ++j) {   // T: j<4 hi rows, j>=4 lo rows
            int rw = (j < 4) ? ((j & 3) * 16 + lr) : (64 + (j & 3) * 16 + lr);
            bf16x8 bfr = *(const bf16x8*)(R1 + rw * 64 + (((kk * 4 + lg) ^ (lr & 7)) << 3));
            y1[0][j & 3] = __builtin_amdgcn_mfma_f32_16x16x32_bf16(afz[kk][0], bfr, y1[0][j & 3], 0, 0, 0);
            y1[1][j & 3] = __builtin_amdgcn_mfma_f32_16x16x32_bf16(afz[kk][1], bfr, y1[1][j & 3], 0, 0, 0);
        }
#pragma unroll
        for (int j = 0; j < 8; ++j) {   // V_hi: j<4 re rows 0..63, j>=4 im rows 64..127
            int rw = (j < 4) ? ((j & 3) * 16 + lr) : (64 + (j & 3) * 16 + lr);
            bf16x8 bfr = *(const bf16x8*)(R2 + rw * 64 + (((kk * 4 + lg) ^ (lr & 7)) << 3));
            ua[0][j] = __builtin_amdgcn_mfma_f32_16x16x32_bf16(afz[kk][0], bfr, ua[0][j], 0, 0, 0);
            ua[1][j] = __builtin_amdgcn_mfma_f32_16x16x32_bf16(afz[kk][1], bfr, ua[1][j], 0, 0, 0);
        }
    }
    __syncthreads();   // B2: T dead, Z-LDS dead (frags in regs)

    // ---- stage V_lo -> R1, E -> Zl ----
#pragma unroll
    for (int it = 0; it < 4; ++it) {    // V_lo = tv rows 256..383
        size_t src = (size_t)h * 24576 + 16384 + (size_t)(it * 256 + tid) * 8;
        gload16(tv + src, (char*)R1 + (it * 256 + wv * 64) * 16);
    }
#pragma unroll
    for (int it = 0; it < 4; ++it) {
        size_t src = (size_t)h * 8192 + (size_t)(it * 256 + tid) * 8;
        gload16(eb + src, (char*)Zl + (it * 256 + wv * 64) * 16);
    }
    __syncthreads();   // B3: V_lo + E arrived

    // ---- GEMM1b: U += Z@V_lo ----
#pragma unroll
    for (int kk = 0; kk < 2; ++kk)
#pragma unroll
        for (int j = 0; j < 8; ++j) {
            int rw = (j < 4) ? ((j & 3) * 16 + lr) : (64 + (j & 3) * 16 + lr);
            bf16x8 bfr = *(const bf16x8*)(R1 + rw * 64 + (((kk * 4 + lg) ^ (lr & 7)) << 3));
            ua[0][j] = __builtin_amdgcn_mfma_f32_16x16x32_bf16(afz[kk][0], bfr, ua[0][j], 0, 0, 0);
            ua[1][j] = __builtin_amdgcn_mfma_f32_16x16x32_bf16(afz[kk][1], bfr, ua[1][j], 0, 0, 0);
        }
    __syncthreads();   // B4: V dead -> R1R2 becomes per-wave scratch

    // ---- per-wave subphases: U(f32)->LDS, scan (f32 regs), W(bf16)->LDS, frags->regs ----
    uint32* Su = (uint32*)(LDSA + 16384 + wv * 8192);   // [16][128] per wave
    bf16x8 afr[2][4];
    float Sre = 0.0f, Sim = 0.0f;
#pragma unroll
    for (int i = 0; i < 2; ++i) {
        // write U exact f32 (rows local 0..15 = tiles i*16..i*16+15)
#pragma unroll
        for (int jj = 0; jj < 8; ++jj)
#pragma unroll
            for (int r = 0; r < 4; ++r) {
                int row = lg * 4 + r;
                int col = (jj & 3) * 16 + lr + ((jj >> 2) << 6);
                Su[row * 128 + (col ^ ((row & 7) << 2))] = __float_as_uint(ua[i][jj][r]);
            }
        // scan 16 tiles; W (state entering tile) written back as single bf16 in slot low-half
#pragma unroll
        for (int r = 0; r < 16; ++r) {
            int sx = (r & 7) << 2;
            int aRe = r * 128 + (lane ^ sx);
            int aIm = r * 128 + ((64 + lane) ^ sx);
            float ur = __uint_as_float(Su[aRe]);
            float ui = __uint_as_float(Su[aIm]);
            Su[aRe] = (uint32)f2bf(Sre);
            Su[aIm] = (uint32)f2bf(Sim);
            float nr = fmaf(ar, Sre, fmaf(-ai, Sim, ur));
            float ni = fmaf(ar, Sim, fmaf(ai, Sre, ui));
            Sre = nr; Sim = ni;
        }
        // build GEMM2 A-fragments (W rows = lr, k = col) into regs
#pragma unroll
        for (int kk = 0; kk < 4; ++kk) {
            int base = kk * 32 + lg * 8;
            int sx = (lr & 7) << 2;
            uint4 ua4 = *(const uint4*)&Su[lr * 128 + (base ^ sx)];
            uint4 ub4 = *(const uint4*)&Su[lr * 128 + ((base + 4) ^ sx)];
            uint4 pk;
            pk.x = __builtin_amdgcn_perm(ua4.y, ua4.x, 0x05040100u);
            pk.y = __builtin_amdgcn_perm(ua4.w, ua4.z, 0x05040100u);
            pk.z = __builtin_amdgcn_perm(ub4.y, ub4.x, 0x05040100u);
            pk.w = __builtin_amdgcn_perm(ub4.w, ub4.z, 0x05040100u);
            afr[i][kk] = *(bf16x8*)&pk;
        }
    }
    __syncthreads();   // B5: all scratch phases done

    // ---- GEMM2: Y2 = W @ E' ----
    f32x4 y2[2][4];
#pragma unroll
    for (int i = 0; i < 2; ++i)
#pragma unroll
        for (int j = 0; j < 4; ++j) y2[i][j] = zf;
#pragma unroll
    for (int kk = 0; kk < 4; ++kk)
#pragma unroll
        for (int j = 0; j < 4; ++j) {
            int rw = j * 16 + lr;
            bf16x8 bfr = *(const bf16x8*)(Zl + rw * 128 + (((kk * 4 + lg) ^ (rw & 7)) << 3));
            y2[0][j] = __builtin_amdgcn_mfma_f32_16x16x32_bf16(afr[0][kk], bfr, y2[0][j], 0, 0, 0);
            y2[1][j] = __builtin_amdgcn_mfma_f32_16x16x32_bf16(afr[1][kk], bfr, y2[1][j], 0, 0, 0);
        }

    // ---- epilogue: y = gelu(Y1 + Y2) -> bounce (overlays scratch; safe post-B5) ----
#pragma unroll
    for (int i = 0; i < 2; ++i)
#pragma unroll
        for (int j = 0; j < 4; ++j)
#pragma unroll
            for (int r = 0; r < 4; ++r) {
                int row = wv * 32 + i * 16 + lg * 4 + r;
                int col = j * 16 + lr;
                float y = y1[i][j][r] + y2[i][j][r];
                YBl[row * 72 + col] = f2bf(gelu_(y));
            }
    __syncthreads();   // B6

    // ---- coalesced flush to yT [b][h][t] ----
#pragma unroll
    for (int it = 0; it < 4; ++it) {
        int c = it * 256 + tid;
        int row = c >> 3, c8 = c & 7;
        int b = mb * 4 + (row >> 5), tile = row & 31;
        uint4 v = *(const uint4*)((const char*)YBl + row * 144 + c8 * 16);
        *(uint4*)(yT + (((size_t)(b * 256 + h)) << 11) + tile * 64 + c8 * 8) = v;
    }
}

// ---------------- transpose yT[b][h][t] bf16 -> yrow[tau][h] bf16 ----------------
__global__ __launch_bounds__(256) void tpose_kernel(const uint32* __restrict__ yT_u,
                                                    uint32* __restrict__ yrow_u) {
    __shared__ uint32 S[64 * 40];
    int tid = threadIdx.x;
    int b = blockIdx.z;
    int h0 = blockIdx.y * 64;
    int tl0 = blockIdx.x * 64;
#pragma unroll
    for (int p = 0; p < 2; ++p) {
        int c = tid + p * 256;
        int hr = c >> 3, c4 = c & 7;
        const uint32* g = yT_u + (size_t)(b * 256 + h0 + hr) * 1024 + (tl0 >> 1) + c4 * 4;
        uint4 v = *(const uint4*)g;
        int col4 = c4 ^ ((hr >> 3) & 7);
        *(uint4*)&S[hr * 40 + col4 * 4] = v;
    }
    __syncthreads();
#pragma unroll
    for (int p = 0; p < 2; ++p) {
        int oc = tid + p * 256;
        int tr = oc >> 3, q8 = oc & 7;
        int tp = tr >> 1;
        uint32 sel = (tr & 1) ? 0x07060302u : 0x05040100u;
        uint4 o;
        uint32* op = (uint32*)&o;
#pragma unroll
        for (int q = 0; q < 4; ++q) {
            int hh = q8 * 8 + 2 * q;
            int c4a = (tp >> 2) ^ (q8 & 7);
            uint32 a = S[hh * 40 + c4a * 4 + (tp & 3)];
            uint32 bq = S[(hh + 1) * 40 + c4a * 4 + (tp & 3)];
            op[q] = __builtin_amdgcn_perm(bq, a, sel);
        }
        size_t tau = (size_t)b * 2048 + tl0 + tr;
        *(uint4*)&yrow_u[tau * 128 + (h0 >> 1) + q8 * 4] = o;
    }
}

// ---------------- gated MFMA GEMM + residual ----------------
__global__ __launch_bounds__(256, 2) void gated_kernel(const unsigned short* __restrict__ yrow,
                                                       const unsigned short* __restrict__ w1b,
                                                       const unsigned short* __restrict__ w2b,
                                                       const float* __restrict__ b1,
                                                       const float* __restrict__ b2,
                                                       float* __restrict__ h) {
    __shared__ unsigned short Al[128 * 32];
    __shared__ unsigned short W1l[128 * 32];
    __shared__ unsigned short W2l[128 * 32];
    int tid = threadIdx.x;
    int lane = tid & 63;
    int wv = tid >> 6;
    int wm = wv >> 1, wn = wv & 1;
    int lr = lane & 15, lg = lane >> 4;
    size_t t0 = (size_t)blockIdx.x * 128;
    int g0 = blockIdx.y * 128;

    f32x4 acc1[4][4], acc2[4][4];
    f32x4 zf = {0.f, 0.f, 0.f, 0.f};
#pragma unroll
    for (int i = 0; i < 4; ++i)
#pragma unroll
        for (int j = 0; j < 4; ++j) { acc1[i][j] = zf; acc2[i][j] = zf; }

    for (int kt = 0; kt < 8; ++kt) {
        __syncthreads();
        int k0 = kt * 32;
#pragma unroll
        for (int p = 0; p < 2; ++p) {
            int c = p * 256 + wv * 64 + lane;
            int row = c >> 2, q = c & 3;
            int ldsoff = (p * 256 + wv * 64) * 16;
            gload16(yrow + (t0 + row) * 256 + k0 + q * 8, (char*)Al + ldsoff);
            gload16(w1b + (size_t)(g0 + row) * 256 + k0 + q * 8, (char*)W1l + ldsoff);
            gload16(w2b + (size_t)(g0 + row) * 256 + k0 + q * 8, (char*)W2l + ldsoff);
        }
        __syncthreads();
        bf16x8 a[4], f1[4], f2[4];
#pragma unroll
        for (int i = 0; i < 4; ++i)
            a[i] = *(const bf16x8*)(Al + (wm * 64 + i * 16 + lr) * 32 + lg * 8);
#pragma unroll
        for (int j = 0; j < 4; ++j) {
            f1[j] = *(const bf16x8*)(W1l + (wn * 64 + j * 16 + lr) * 32 + lg * 8);
            f2[j] = *(const bf16x8*)(W2l + (wn * 64 + j * 16 + lr) * 32 + lg * 8);
        }
#pragma unroll
        for (int i = 0; i < 4; ++i)
#pragma unroll
            for (int j = 0; j < 4; ++j) {
                acc1[i][j] = __builtin_amdgcn_mfma_f32_16x16x32_bf16(a[i], f1[j], acc1[i][j], 0, 0, 0);
                acc2[i][j] = __builtin_amdgcn_mfma_f32_16x16x32_bf16(a[i], f2[j], acc2[i][j], 0, 0, 0);
            }
    }

    float bb1[4], bb2[4];
#pragma unroll
    for (int j = 0; j < 4; ++j) {
        int g = g0 + wn * 64 + j * 16 + lr;
        bb1[j] = b1[g];
        bb2[j] = b2[g];
    }
#pragma unroll
    for (int i = 0; i < 4; ++i)
#pragma unroll
        for (int j = 0; j < 4; ++j) {
            int g = g0 + wn * 64 + j * 16 + lr;
#pragma unroll
            for (int r = 0; r < 4; ++r) {
                size_t t = t0 + wm * 64 + i * 16 + lg * 4 + r;
                float p1 = acc1[i][j][r] + bb1[j];
                float p2 = acc2[i][j][r] + bb2[j];
                float* hp = &h[t * Hh + g];
                *hp = fmaf(p1, sigmoidf_(p2), *hp);
            }
        }
}

// ---------------- decoder ----------------
__global__ __launch_bounds__(256) void dec_kernel(const float* __restrict__ h,
                                                  const float* __restrict__ dec_w,
                                                  const float* __restrict__ dec_b,
                                                  float* __restrict__ out) {
    __shared__ float wT[256][36];
    __shared__ float hs[64][20];
    int tid = threadIdx.x;
    for (int idx = tid; idx < OUTD * Hh; idx += 256) {
        int o = idx >> 8, k = idx & 255;
        wT[k][o] = dec_w[idx];
    }
    size_t t0 = (size_t)blockIdx.x * 64;
    int tl = tid & 63, og = tid >> 6;
    float acc[9];
#pragma unroll
    for (int j = 0; j < 9; ++j) acc[j] = 0.0f;
    int i = tid >> 2, c = (tid & 3) * 4;
    for (int kt = 0; kt < 16; ++kt) {
        __syncthreads();
        *(float4*)&hs[i][c] = *(const float4*)&h[(t0 + i) * Hh + kt * 16 + c];
        __syncthreads();
#pragma unroll
        for (int k2 = 0; k2 < 16; ++k2) {
            float a = hs[tl][k2];
            int kk = kt * 16 + k2;
#pragma unroll
            for (int j = 0; j < 9; ++j) acc[j] = fmaf(a, wT[kk][og + 4 * j], acc[j]);
        }
    }
#pragma unroll
    for (int j = 0; j < 9; ++j) {
        int o = og + 4 * j;
        if (o < OUTD) out[(t0 + tl) * OUTD + o] = acc[j] + dec_b[o];
    }
}

extern "C" void kernel_launch(void* const* d_in, const int* in_sizes, int n_in,
                              void* d_out, int out_size, void* d_ws, size_t ws_size,
                              hipStream_t stream) {
    const float* x = (const float*)d_in[0];
    const float* enc_w = (const float*)d_in[1];
    const float* enc_b = (const float*)d_in[2];
    const float* lre = (const float*)d_in[3];
    const float* lim = (const float*)d_in[4];
    const float* cre = (const float*)d_in[5];
    const float* cim = (const float*)d_in[6];
    const float* dd = (const float*)d_in[7];
    const float* ls = (const float*)d_in[8];
    const float* lns = (const float*)d_in[9];
    const float* lnb = (const float*)d_in[10];
    const float* w1 = (const float*)d_in[11];
    const float* b1 = (const float*)d_in[12];
    const float* w2 = (const float*)d_in[13];
    const float* b2 = (const float*)d_in[14];
    const float* dw = (const float*)d_in[15];
    const float* db = (const float*)d_in[16];
    float* out = (float*)d_out;

    const size_t NTOK = (size_t)Bb * Lq;
    float* hbuf = (float*)d_ws;                                   // 32MB fp32
    unsigned short* zT = (unsigned short*)(hbuf + NTOK * Hh);     // 16MB bf16 [b][h][t] (swizzled chunks)
    unsigned short* yT = zT + NTOK * Hh;                          // 16MB bf16 [b][h][t]
    unsigned short* wbf = yT + NTOK * Hh;                         // 1MB bf16 gated weights
    unsigned short* tv_slab = wbf + 524288;                       // 256*24576 bf16 = 12.6MB
    unsigned short* eb_slab = tv_slab + 6291456;                  // 256*8192 bf16 = 4.2MB
    float* da64 = (float*)(eb_slab + 2097152);                    // 256*128 f32
    unsigned short* yrow = zT;                                    // reuse zT region after ssm

    wconv_kernel<<<128, 256, 0, stream>>>(w1, w2, wbf);
    enc_kernel<<<(int)(NTOK / 8), 256, 0, stream>>>(x, enc_w, enc_b, hbuf);
    for (int il = 0; il < NLay; ++il) {
        k1_kernel<<<256, 256, 0, stream>>>(lre + il * 16384, lim + il * 16384,
                                           cre + il * 16384, cim + il * 16384,
                                           dd + il * Hh, ls + il * Hh,
                                           tv_slab, eb_slab, da64);
        lnt_kernel<<<(int)(NTOK / 32), 256, 0, stream>>>(hbuf, lns + il * Hh, lnb + il * Hh,
                                                         (uint32*)zT);
        ssm_kernel<<<dim3(256, 4), 256, 0, stream>>>(zT, tv_slab, eb_slab, da64, yT);
        tpose_kernel<<<dim3(32, 4, 16), 256, 0, stream>>>((const uint32*)yT, (uint32*)yrow);
        gated_kernel<<<dim3(256, 2), 256, 0, stream>>>(yrow,
                                                       wbf + il * 65536,
                                                       wbf + 262144 + il * 65536,
                                                       b1 + il * Hh, b2 + il * Hh, hbuf);
    }
    dec_kernel<<<(int)(NTOK / 64), 256, 0, stream>>>(hbuf, dw, db, out);
}

// Round 6
// 502.544 us; speedup vs baseline: 2.6378x; 1.1723x over previous
//
#include <hip/hip_runtime.h>
#include <hip/hip_bf16.h>

#define Bb 16
#define Lq 2048
#define Hh 256
#define NLay 4
#define IND 40
#define OUTD 33

typedef unsigned int uint32;
typedef unsigned short ushort_t;

typedef short bf16x8 __attribute__((ext_vector_type(8)));
typedef float f32x4 __attribute__((ext_vector_type(4)));

__device__ __forceinline__ float sigmoidf_(float x) {
    return 1.0f / (1.0f + __expf(-x));
}
__device__ __forceinline__ float gelu_(float x) {
    float x2 = x * x;
    float u = x * fmaf(0.0713548162726f, x2, 1.5957691216057308f);
    return x * sigmoidf_(u);
}
__device__ __forceinline__ unsigned short f2bf(float f) {
    uint32 u = __float_as_uint(f);
    return (unsigned short)((u + 0x7fffu + ((u >> 16) & 1u)) >> 16);
}
__device__ __forceinline__ float bf2f(unsigned short s) {
    return __uint_as_float(((uint32)s) << 16);
}
__device__ __forceinline__ void gload16(const void* g, void* l) {
    __builtin_amdgcn_global_load_lds(
        (const __attribute__((address_space(1))) unsigned int*)g,
        (__attribute__((address_space(3))) unsigned int*)l, 16, 0, 0);
}

// ---------------- encoder ----------------
__global__ __launch_bounds__(256) void enc_kernel(const float* __restrict__ x,
                                                  const float* __restrict__ enc_w,
                                                  const float* __restrict__ enc_b,
                                                  float* __restrict__ h) {
    __shared__ float xs[8 * IND];
    int tid = threadIdx.x;
    int t0 = blockIdx.x * 8;
    for (int i = tid; i < 8 * IND; i += 256) xs[i] = x[t0 * IND + i];
    float w[IND];
    const float4* w4 = (const float4*)(enc_w + tid * IND);
#pragma unroll
    for (int c = 0; c < 10; ++c) {
        float4 v = w4[c];
        w[4 * c] = v.x; w[4 * c + 1] = v.y; w[4 * c + 2] = v.z; w[4 * c + 3] = v.w;
    }
    float bias = enc_b[tid];
    __syncthreads();
#pragma unroll
    for (int t = 0; t < 8; ++t) {
        float acc = bias;
#pragma unroll
        for (int i = 0; i < IND; ++i) acc = fmaf(xs[t * IND + i], w[i], acc);
        h[(size_t)(t0 + t) * Hh + tid] = acc;
    }
}

// ---------------- weight fp32->bf16 conversion ----------------
__global__ __launch_bounds__(256) void wconv_kernel(const float* __restrict__ w1,
                                                    const float* __restrict__ w2,
                                                    unsigned short* __restrict__ o) {
    int idx = blockIdx.x * 256 + threadIdx.x;
    for (int i = idx; i < 65536; i += 32768) {
        float4 a = ((const float4*)w1)[i];
        ushort4 u;
        u.x = f2bf(a.x); u.y = f2bf(a.y); u.z = f2bf(a.z); u.w = f2bf(a.w);
        ((ushort4*)o)[i] = u;
        float4 b4 = ((const float4*)w2)[i];
        ushort4 v;
        v.x = f2bf(b4.x); v.y = f2bf(b4.y); v.z = f2bf(b4.z); v.w = f2bf(b4.w);
        ((ushort4*)(o + 262144))[i] = v;
    }
}

// ---------------- layernorm + transpose: h[t][H] fp32 -> zT[b][h][t] bf16 (chunk-swizzled) ----------------
__global__ __launch_bounds__(256) void lnt_kernel(const float* __restrict__ h,
                                                  const float* __restrict__ scale,
                                                  const float* __restrict__ bias,
                                                  uint32* __restrict__ zT_u) {
    __shared__ float T[32 * 260];
    __shared__ float musab[64];
    __shared__ float scb[512];
    int tid = threadIdx.x, lane = tid & 63, wv = tid >> 6;
    size_t t0 = (size_t)blockIdx.x * 32;
    int b = (int)(t0 >> 11);
    int tloc = (int)(t0 & 2047);
    scb[tid] = scale[tid];
    scb[256 + tid] = bias[tid];
#pragma unroll
    for (int p = 0; p < 8; ++p) {
        int idx = tid + p * 256;
        int r = idx >> 6, c4 = idx & 63;
        float4 v = *(const float4*)&h[(t0 + r) * Hh + c4 * 4];
        *(float4*)&T[r * 260 + c4 * 4] = v;
    }
    __syncthreads();
    for (int tok = wv; tok < 32; tok += 4) {
        float4 v = *(const float4*)&T[tok * 260 + lane * 4];
        float s = (v.x + v.y) + (v.z + v.w);
        float q = fmaf(v.x, v.x, fmaf(v.y, v.y, fmaf(v.z, v.z, v.w * v.w)));
#pragma unroll
        for (int m = 1; m < 64; m <<= 1) {
            s += __shfl_xor(s, m, 64);
            q += __shfl_xor(q, m, 64);
        }
        if (lane == 0) {
            float mu = s * (1.0f / 256.0f);
            float var = q * (1.0f / 256.0f) - mu * mu;
            musab[tok] = mu;
            musab[32 + tok] = rsqrtf(var + 1e-5f);
        }
    }
    __syncthreads();
#pragma unroll
    for (int j = 0; j < 16; ++j) {
        int hh = wv * 64 + j * 4 + (lane >> 4);
        int tp = lane & 15;
        float v0 = T[(2 * tp) * 260 + hh];
        float v1 = T[(2 * tp + 1) * 260 + hh];
        float m0 = musab[2 * tp], r0 = musab[32 + 2 * tp];
        float m1 = musab[2 * tp + 1], r1 = musab[33 + 2 * tp];
        float sc = scb[hh], bi = scb[256 + hh];
        float o0 = fmaf((v0 - m0) * r0, sc, bi);
        float o1 = fmaf((v1 - m1) * r1, sc, bi);
        uint32 pk = ((uint32)f2bf(o1) << 16) | (uint32)f2bf(o0);
        uint32 u = (uint32)((tloc >> 1) + tp);
        // bake ssm's LDS chunk swizzle: 16B chunk c within 64-token tile stored at c ^ (tile&7)
        uint32 usw = (u & ~28u) | ((((u >> 2) & 7u) ^ ((u >> 5) & 7u)) << 2);
        zT_u[(size_t)(b * 256 + hh) * 1024 + usw] = pk;
    }
}

// ---------------- k1 (ALL LAYERS batched): per-(layer,h) chunked-scan matrices ----------------
// tv[il][h] = [384][64]: 0..63 T_hi; 64..127 T_lo; 128..191 Vre_hi; 192..255 Vim_hi;
//                        256..319 Vre_lo; 320..383 Vim_lo
// eb[il][h] = [64][128]: E'(l,n)=2Re(dA^{l+1}), E'(l,64+n)=-2Im(dA^{l+1}); da64[il][h][2][64]
__global__ __launch_bounds__(256) void k1_kernel(const float* __restrict__ lre_p,
                                                 const float* __restrict__ lim_p,
                                                 const float* __restrict__ cre_p,
                                                 const float* __restrict__ cim_p,
                                                 const float* __restrict__ d_p,
                                                 const float* __restrict__ ls_p,
                                                 unsigned short* __restrict__ tv,
                                                 unsigned short* __restrict__ eb,
                                                 float* __restrict__ da64) {
    __shared__ float aa[64], tt[64], Gr[64], Gi[64], ks[64];
    int il = blockIdx.x >> 8;
    int h = blockIdx.x & 255;
    lre_p += (size_t)il * 16384; lim_p += (size_t)il * 16384;
    cre_p += (size_t)il * 16384; cim_p += (size_t)il * 16384;
    d_p += il * Hh; ls_p += il * Hh;
    tv += (size_t)il * 6291456;
    eb += (size_t)il * 2097152;
    da64 += (size_t)il * 32768;
    int tid = threadIdx.x;
    int lane = tid & 63, q = tid >> 6;
    if (tid < 64) {
        int n = tid;
        float lre = lre_p[h * 64 + n], lim = lim_p[h * 64 + n];
        float cre = cre_p[h * 64 + n], cim = cim_p[h * 64 + n];
        float dt = expf(ls_p[h]);
        float a = lre * dt, th = lim * dt;
        float er = expf(a);
        float s, c;
        sincosf(th, &s, &c);
        float dAre = er * c, dAim = er * s;
        float inv = 1.0f / (lre * lre + lim * lim);
        float dBre = ((dAre - 1.0f) * lre + dAim * lim) * inv;
        float dBim = (dAim * lre - (dAre - 1.0f) * lim) * inv;
        aa[n] = a; tt[n] = th;
        Gr[n] = cre * dBre - cim * dBim;
        Gi[n] = cre * dBim + cim * dBre;
    }
    __syncthreads();
    {
        float a = aa[lane], th = tt[lane], gr = Gr[lane], gi = Gi[lane];
        for (int mm = 0; mm < 16; ++mm) {
            int m = q * 16 + mm;
            float er = expf(m * a);
            float s, c;
            sincosf(m * th, &s, &c);
            float v = gr * (er * c) - gi * (er * s);
#pragma unroll
            for (int msk = 1; msk < 64; msk <<= 1) v += __shfl_xor(v, msk, 64);
            if (lane == 0) ks[m] = 2.0f * v;
        }
    }
    __syncthreads();
    float dh = d_p[h];
    size_t basep = (size_t)h * 24576;
#pragma unroll
    for (int i2 = 0; i2 < 16; ++i2) {   // T' hi + lo
        int e = tid + i2 * 256;
        int l = e >> 6, j = e & 63;
        float v = (j < l) ? ks[l - j] : (j == l ? ks[0] + dh : 0.0f);
        int sj = (((j >> 3) ^ (l & 7)) << 3) | (j & 7);
        unsigned short hi = f2bf(v);
        tv[basep + l * 64 + sj] = hi;
        tv[basep + (64 + l) * 64 + sj] = f2bf(v - bf2f(hi));
    }
#pragma unroll
    for (int i2 = 0; i2 < 32; ++i2) {   // V' hi + lo
        int e = tid + i2 * 256;
        int part = e >> 12, n = (e >> 6) & 63, j = e & 63;
        int m = 63 - j;
        float er = expf(m * aa[n]);
        float s, c;
        sincosf(m * tt[n], &s, &c);
        float pre = er * c, pim = er * s;
        float v = part ? (Gr[n] * pim + Gi[n] * pre) : (Gr[n] * pre - Gi[n] * pim);
        int sj = (((j >> 3) ^ (n & 7)) << 3) | (j & 7);
        unsigned short hi = f2bf(v);
        tv[basep + (size_t)(128 + part * 64 + n) * 64 + sj] = hi;
        tv[basep + (size_t)(256 + part * 64 + n) * 64 + sj] = f2bf(v - bf2f(hi));
    }
#pragma unroll
    for (int i2 = 0; i2 < 32; ++i2) {   // E'
        int e = tid + i2 * 256;
        int l = e >> 7, k = e & 127;
        int n = k & 63, m = l + 1;
        float er = expf(m * aa[n]);
        float s, c;
        sincosf(m * tt[n], &s, &c);
        float v = (k < 64) ? 2.0f * er * c : -2.0f * er * s;
        eb[(size_t)h * 8192 + l * 128 + ((((k >> 3) ^ (l & 7)) << 3) | (k & 7))] = f2bf(v);
    }
    if (tid < 64) {
        int n = tid;
        float er = expf(64.0f * aa[n]);
        float s, c;
        sincosf(64.0f * tt[n], &s, &c);
        da64[h * 128 + n] = er * c;
        da64[h * 128 + 64 + n] = er * s;
    }
}

// ---------------- fused SSM (chunked scan, MFMA, 48KB LDS, per-wave f32 scratch): zT -> yT ----------------
__global__ __launch_bounds__(256, 3) void ssm_kernel(const unsigned short* __restrict__ zT,
                                                     const unsigned short* __restrict__ tv,
                                                     const unsigned short* __restrict__ eb,
                                                     const float* __restrict__ da64,
                                                     unsigned short* __restrict__ yT) {
    static __shared__ __align__(16) char LDSA[49152];
    ushort_t* Zl = (ushort_t*)LDSA;              // [128][64] Z -> later E [64][128]
    ushort_t* R1 = (ushort_t*)(LDSA + 16384);    // T [128][64] -> V_lo [128][64]
    ushort_t* R2 = (ushort_t*)(LDSA + 32768);    // V_hi [128][64]
    ushort_t* YBl = (ushort_t*)(LDSA + 16384);   // [128][72] y bounce (post-scratch)
    int tid = threadIdx.x;
    int lane = tid & 63, wv = tid >> 6;
    int lr = lane & 15, lg = lane >> 4;
    int h = blockIdx.x, mb = blockIdx.y;

    float ar = da64[h * 128 + lane];
    float ai = da64[h * 128 + 64 + lane];

    // ---- stage Z (16KB), T (16KB), V_hi (16KB) ----
#pragma unroll
    for (int it = 0; it < 4; ++it) {
        int c = it * 256 + tid;
        int r = c >> 3, s = c & 7;
        int b = mb * 4 + (r >> 5), tile = r & 31;
        size_t src = ((size_t)(b * 256 + h) << 11) + tile * 64 + s * 8;
        gload16(zT + src, (char*)Zl + (it * 256 + wv * 64) * 16);
    }
#pragma unroll
    for (int it = 0; it < 4; ++it) {    // T rows 0..127
        size_t src = (size_t)h * 24576 + (size_t)(it * 256 + tid) * 8;
        gload16(tv + src, (char*)R1 + (it * 256 + wv * 64) * 16);
    }
#pragma unroll
    for (int it = 0; it < 4; ++it) {    // V_hi = tv rows 128..255
        size_t src = (size_t)h * 24576 + 8192 + (size_t)(it * 256 + tid) * 8;
        gload16(tv + src, (char*)R2 + (it * 256 + wv * 64) * 16);
    }
    __syncthreads();   // B1

    // ---- A-fragments of Z (held in regs for GEMM1 hi+lo phases) ----
    bf16x8 afz[2][2];  // [kk][rowblock]
#pragma unroll
    for (int kk = 0; kk < 2; ++kk) {
        int row0 = wv * 32 + lr;
        int row1 = row0 + 16;
        afz[kk][0] = *(const bf16x8*)(Zl + row0 * 64 + (((kk * 4 + lg) ^ (row0 & 7)) << 3));
        afz[kk][1] = *(const bf16x8*)(Zl + row1 * 64 + (((kk * 4 + lg) ^ (row1 & 7)) << 3));
    }

    f32x4 y1[2][4], ua[2][8];
    f32x4 zf = {0.f, 0.f, 0.f, 0.f};
#pragma unroll
    for (int i = 0; i < 2; ++i) {
#pragma unroll
        for (int j = 0; j < 4; ++j) y1[i][j] = zf;
#pragma unroll
        for (int j = 0; j < 8; ++j) ua[i][j] = zf;
    }

    // ---- GEMM1a: Y1 = Z@(T_hi+T_lo);  U += Z@V_hi ----
#pragma unroll
    for (int kk = 0; kk < 2; ++kk) {
#pragma unroll
        for (int j = 0; j < 8; ++j) {   // T: j<4 hi rows, j>=4 lo rows
            int rw = (j < 4) ? ((j & 3) * 16 + lr) : (64 + (j & 3) * 16 + lr);
            bf16x8 bfr = *(const bf16x8*)(R1 + rw * 64 + (((kk * 4 + lg) ^ (lr & 7)) << 3));
            y1[0][j & 3] = __builtin_amdgcn_mfma_f32_16x16x32_bf16(afz[kk][0], bfr, y1[0][j & 3], 0, 0, 0);
            y1[1][j & 3] = __builtin_amdgcn_mfma_f32_16x16x32_bf16(afz[kk][1], bfr, y1[1][j & 3], 0, 0, 0);
        }
#pragma unroll
        for (int j = 0; j < 8; ++j) {   // V_hi: j<4 re rows 0..63, j>=4 im rows 64..127
            int rw = (j < 4) ? ((j & 3) * 16 + lr) : (64 + (j & 3) * 16 + lr);
            bf16x8 bfr = *(const bf16x8*)(R2 + rw * 64 + (((kk * 4 + lg) ^ (lr & 7)) << 3));
            ua[0][j] = __builtin_amdgcn_mfma_f32_16x16x32_bf16(afz[kk][0], bfr, ua[0][j], 0, 0, 0);
            ua[1][j] = __builtin_amdgcn_mfma_f32_16x16x32_bf16(afz[kk][1], bfr, ua[1][j], 0, 0, 0);
        }
    }
    __syncthreads();   // B2: T dead, Z-LDS dead (frags in regs)

    // ---- stage V_lo -> R1, E -> Zl ----
#pragma unroll
    for (int it = 0; it < 4; ++it) {    // V_lo = tv rows 256..383
        size_t src = (size_t)h * 24576 + 16384 + (size_t)(it * 256 + tid) * 8;
        gload16(tv + src, (char*)R1 + (it * 256 + wv * 64) * 16);
    }
#pragma unroll
    for (int it = 0; it < 4; ++it) {
        size_t src = (size_t)h * 8192 + (size_t)(it * 256 + tid) * 8;
        gload16(eb + src, (char*)Zl + (it * 256 + wv * 64) * 16);
    }
    __syncthreads();   // B3: V_lo + E arrived

    // ---- GEMM1b: U += Z@V_lo ----
#pragma unroll
    for (int kk = 0; kk < 2; ++kk)
#pragma unroll
        for (int j = 0; j < 8; ++j) {
            int rw = (j < 4) ? ((j & 3) * 16 + lr) : (64 + (j & 3) * 16 + lr);
            bf16x8 bfr = *(const bf16x8*)(R1 + rw * 64 + (((kk * 4 + lg) ^ (lr & 7)) << 3));
            ua[0][j] = __builtin_amdgcn_mfma_f32_16x16x32_bf16(afz[kk][0], bfr, ua[0][j], 0, 0, 0);
            ua[1][j] = __builtin_amdgcn_mfma_f32_16x16x32_bf16(afz[kk][1], bfr, ua[1][j], 0, 0, 0);
        }
    __syncthreads();   // B4: V dead -> R1R2 becomes per-wave scratch

    // ---- per-wave subphases: U(f32)->LDS, scan (f32 regs), W(bf16)->LDS, frags->regs ----
    uint32* Su = (uint32*)(LDSA + 16384 + wv * 8192);   // [16][128] per wave
    bf16x8 afr[2][4];
    float Sre = 0.0f, Sim = 0.0f;
#pragma unroll
    for (int i = 0; i < 2; ++i) {
        // write U exact f32 (rows local 0..15 = tiles i*16..i*16+15)
#pragma unroll
        for (int jj = 0; jj < 8; ++jj)
#pragma unroll
            for (int r = 0; r < 4; ++r) {
                int row = lg * 4 + r;
                int col = (jj & 3) * 16 + lr + ((jj >> 2) << 6);
                Su[row * 128 + (col ^ ((row & 7) << 2))] = __float_as_uint(ua[i][jj][r]);
            }
        // scan 16 tiles; W (state entering tile) written back as single bf16 in slot low-half
#pragma unroll
        for (int r = 0; r < 16; ++r) {
            int sx = (r & 7) << 2;
            int aRe = r * 128 + (lane ^ sx);
            int aIm = r * 128 + ((64 + lane) ^ sx);
            float ur = __uint_as_float(Su[aRe]);
            float ui = __uint_as_float(Su[aIm]);
            Su[aRe] = (uint32)f2bf(Sre);
            Su[aIm] = (uint32)f2bf(Sim);
            float nr = fmaf(ar, Sre, fmaf(-ai, Sim, ur));
            float ni = fmaf(ar, Sim, fmaf(ai, Sre, ui));
            Sre = nr; Sim = ni;
        }
        // build GEMM2 A-fragments (W rows = lr, k = col) into regs
#pragma unroll
        for (int kk = 0; kk < 4; ++kk) {
            int base = kk * 32 + lg * 8;
            int sx = (lr & 7) << 2;
            uint4 ua4 = *(const uint4*)&Su[lr * 128 + (base ^ sx)];
            uint4 ub4 = *(const uint4*)&Su[lr * 128 + ((base + 4) ^ sx)];
            uint4 pk;
            pk.x = __builtin_amdgcn_perm(ua4.y, ua4.x, 0x05040100u);
            pk.y = __builtin_amdgcn_perm(ua4.w, ua4.z, 0x05040100u);
            pk.z = __builtin_amdgcn_perm(ub4.y, ub4.x, 0x05040100u);
            pk.w = __builtin_amdgcn_perm(ub4.w, ub4.z, 0x05040100u);
            afr[i][kk] = *(bf16x8*)&pk;
        }
    }
    __syncthreads();   // B5: all scratch phases done

    // ---- GEMM2: Y2 = W @ E' ----
    f32x4 y2[2][4];
#pragma unroll
    for (int i = 0; i < 2; ++i)
#pragma unroll
        for (int j = 0; j < 4; ++j) y2[i][j] = zf;
#pragma unroll
    for (int kk = 0; kk < 4; ++kk)
#pragma unroll
        for (int j = 0; j < 4; ++j) {
            int rw = j * 16 + lr;
            bf16x8 bfr = *(const bf16x8*)(Zl + rw * 128 + (((kk * 4 + lg) ^ (rw & 7)) << 3));
            y2[0][j] = __builtin_amdgcn_mfma_f32_16x16x32_bf16(afr[0][kk], bfr, y2[0][j], 0, 0, 0);
            y2[1][j] = __builtin_amdgcn_mfma_f32_16x16x32_bf16(afr[1][kk], bfr, y2[1][j], 0, 0, 0);
        }

    // ---- epilogue: y = gelu(Y1 + Y2) -> bounce (overlays scratch; safe post-B5) ----
#pragma unroll
    for (int i = 0; i < 2; ++i)
#pragma unroll
        for (int j = 0; j < 4; ++j)
#pragma unroll
            for (int r = 0; r < 4; ++r) {
                int row = wv * 32 + i * 16 + lg * 4 + r;
                int col = j * 16 + lr;
                float y = y1[i][j][r] + y2[i][j][r];
                YBl[row * 72 + col] = f2bf(gelu_(y));
            }
    __syncthreads();   // B6

    // ---- coalesced flush to yT [b][h][t] ----
#pragma unroll
    for (int it = 0; it < 4; ++it) {
        int c = it * 256 + tid;
        int row = c >> 3, c8 = c & 7;
        int b = mb * 4 + (row >> 5), tile = row & 31;
        uint4 v = *(const uint4*)((const char*)YBl + row * 144 + c8 * 16);
        *(uint4*)(yT + (((size_t)(b * 256 + h)) << 11) + tile * 64 + c8 * 8) = v;
    }
}

// ---------------- gated MFMA GEMM + residual, reading yT[b][h][t] directly ----------------
// A-tile staged subtiled [hblk 8][tc 8] x [4h][16t] (128B blocks) via per-lane-src gload16;
// A-fragments built with ds_read_b64_tr_b16 (lane lr = t-col, 4 h's per read).
__global__ __launch_bounds__(256, 2) void gated_kernel(const unsigned short* __restrict__ yT,
                                                       const unsigned short* __restrict__ w1b,
                                                       const unsigned short* __restrict__ w2b,
                                                       const float* __restrict__ b1,
                                                       const float* __restrict__ b2,
                                                       float* __restrict__ h) {
    __shared__ __align__(16) unsigned short Al[4096];
    __shared__ __align__(16) unsigned short W1l[4096];
    __shared__ __align__(16) unsigned short W2l[4096];
    int tid = threadIdx.x;
    int lane = tid & 63;
    int wv = tid >> 6;
    int wm = wv >> 1, wn = wv & 1;
    int lr = lane & 15, lg = lane >> 4;
    size_t t0 = (size_t)blockIdx.x * 128;
    int bsel = (int)(t0 >> 11);
    int tloc0 = (int)(t0 & 2047);
    int g0 = blockIdx.y * 128;

    f32x4 acc1[4][4], acc2[4][4];
    f32x4 zf = {0.f, 0.f, 0.f, 0.f};
#pragma unroll
    for (int i = 0; i < 4; ++i)
#pragma unroll
        for (int j = 0; j < 4; ++j) { acc1[i][j] = zf; acc2[i][j] = zf; }

    uint32 abase = (uint32)(size_t)(__attribute__((address_space(3))) unsigned short*)Al;

    for (int kt = 0; kt < 8; ++kt) {
        __syncthreads();
        int k0 = kt * 32;
#pragma unroll
        for (int p = 0; p < 2; ++p) {
            int s = p * 256 + tid;
            int ldsoff = (p * 256 + wv * 64) * 16;
            // A: slot s -> block bi=(hblk*8+tc), within-block 16B slot w
            {
                int bi = s >> 3, w = s & 7;
                int hblk = bi >> 3, tc = bi & 7;
                int ha = hblk * 4 + (w >> 1);
                int toff = tc * 16 + (w & 1) * 8;
                gload16(yT + (((size_t)(bsel * 256 + k0 + ha)) << 11) + tloc0 + toff,
                        (char*)Al + ldsoff);
            }
            // W: paired-row (128B line) chunk swizzle ^(L&7), baked into per-lane src
            {
                int L = s >> 3, cs = s & 7;
                int cu = cs ^ (L & 7);
                int row = L * 2 + (cu >> 2), q = cu & 3;
                gload16(w1b + (size_t)(g0 + row) * 256 + k0 + q * 8, (char*)W1l + ldsoff);
                gload16(w2b + (size_t)(g0 + row) * 256 + k0 + q * 8, (char*)W2l + ldsoff);
            }
        }
        __syncthreads();
        bf16x8 a[4], f1[4], f2[4];
#pragma unroll
        for (int i = 0; i < 4; ++i) {
            int tc = wm * 4 + i;
            uint32 a0 = abase + (uint32)((lg * 2 * 8 + tc) * 128 + lr * 8);
            uint32 a1 = a0 + 1024;   // next hblk
            uint2 d0, d1;
            asm volatile("ds_read_b64_tr_b16 %0, %2\n\t"
                         "ds_read_b64_tr_b16 %1, %3\n\t"
                         "s_waitcnt lgkmcnt(0)"
                         : "=&v"(d0), "=&v"(d1)
                         : "v"(a0), "v"(a1));
            uint4 pk;
            pk.x = d0.x; pk.y = d0.y; pk.z = d1.x; pk.w = d1.y;
            a[i] = *(bf16x8*)&pk;
        }
#pragma unroll
        for (int j = 0; j < 4; ++j) {
            int row = wn * 64 + j * 16 + lr;
            int wadr = (row >> 1) * 64 + ((((row & 1) * 4 + lg) ^ ((row >> 1) & 7)) << 3);
            f1[j] = *(const bf16x8*)(W1l + wadr);
            f2[j] = *(const bf16x8*)(W2l + wadr);
        }
#pragma unroll
        for (int i = 0; i < 4; ++i)
#pragma unroll
            for (int j = 0; j < 4; ++j) {
                acc1[i][j] = __builtin_amdgcn_mfma_f32_16x16x32_bf16(a[i], f1[j], acc1[i][j], 0, 0, 0);
                acc2[i][j] = __builtin_amdgcn_mfma_f32_16x16x32_bf16(a[i], f2[j], acc2[i][j], 0, 0, 0);
            }
    }

    float bb1[4], bb2[4];
#pragma unroll
    for (int j = 0; j < 4; ++j) {
        int g = g0 + wn * 64 + j * 16 + lr;
        bb1[j] = b1[g];
        bb2[j] = b2[g];
    }
#pragma unroll
    for (int i = 0; i < 4; ++i)
#pragma unroll
        for (int j = 0; j < 4; ++j) {
            int g = g0 + wn * 64 + j * 16 + lr;
#pragma unroll
            for (int r = 0; r < 4; ++r) {
                size_t t = t0 + wm * 64 + i * 16 + lg * 4 + r;
                float p1 = acc1[i][j][r] + bb1[j];
                float p2 = acc2[i][j][r] + bb2[j];
                float* hp = &h[t * Hh + g];
                *hp = fmaf(p1, sigmoidf_(p2), *hp);
            }
        }
}

// ---------------- decoder ----------------
__global__ __launch_bounds__(256) void dec_kernel(const float* __restrict__ h,
                                                  const float* __restrict__ dec_w,
                                                  const float* __restrict__ dec_b,
                                                  float* __restrict__ out) {
    __shared__ float wT[256][36];
    __shared__ float hs[64][20];
    int tid = threadIdx.x;
    for (int idx = tid; idx < OUTD * Hh; idx += 256) {
        int o = idx >> 8, k = idx & 255;
        wT[k][o] = dec_w[idx];
    }
    size_t t0 = (size_t)blockIdx.x * 64;
    int tl = tid & 63, og = tid >> 6;
    float acc[9];
#pragma unroll
    for (int j = 0; j < 9; ++j) acc[j] = 0.0f;
    int i = tid >> 2, c = (tid & 3) * 4;
    for (int kt = 0; kt < 16; ++kt) {
        __syncthreads();
        *(float4*)&hs[i][c] = *(const float4*)&h[(t0 + i) * Hh + kt * 16 + c];
        __syncthreads();
#pragma unroll
        for (int k2 = 0; k2 < 16; ++k2) {
            float a = hs[tl][k2];
            int kk = kt * 16 + k2;
#pragma unroll
            for (int j = 0; j < 9; ++j) acc[j] = fmaf(a, wT[kk][og + 4 * j], acc[j]);
        }
    }
#pragma unroll
    for (int j = 0; j < 9; ++j) {
        int o = og + 4 * j;
        if (o < OUTD) out[(t0 + tl) * OUTD + o] = acc[j] + dec_b[o];
    }
}

extern "C" void kernel_launch(void* const* d_in, const int* in_sizes, int n_in,
                              void* d_out, int out_size, void* d_ws, size_t ws_size,
                              hipStream_t stream) {
    const float* x = (const float*)d_in[0];
    const float* enc_w = (const float*)d_in[1];
    const float* enc_b = (const float*)d_in[2];
    const float* lre = (const float*)d_in[3];
    const float* lim = (const float*)d_in[4];
    const float* cre = (const float*)d_in[5];
    const float* cim = (const float*)d_in[6];
    const float* dd = (const float*)d_in[7];
    const float* ls = (const float*)d_in[8];
    const float* lns = (const float*)d_in[9];
    const float* lnb = (const float*)d_in[10];
    const float* w1 = (const float*)d_in[11];
    const float* b1 = (const float*)d_in[12];
    const float* w2 = (const float*)d_in[13];
    const float* b2 = (const float*)d_in[14];
    const float* dw = (const float*)d_in[15];
    const float* db = (const float*)d_in[16];
    float* out = (float*)d_out;

    const size_t NTOK = (size_t)Bb * Lq;
    float* hbuf = (float*)d_ws;                                   // 32MB fp32
    unsigned short* zT = (unsigned short*)(hbuf + NTOK * Hh);     // 16MB bf16 [b][h][t] (swizzled chunks)
    unsigned short* yT = zT + NTOK * Hh;                          // 16MB bf16 [b][h][t] (linear)
    unsigned short* wbf = yT + NTOK * Hh;                         // 1MB bf16 gated weights
    unsigned short* tv_slab = wbf + 524288;                       // 4 layers x 6291456 ush = 50MB
    unsigned short* eb_slab = tv_slab + (size_t)4 * 6291456;      // 4 x 2097152 ush = 17MB
    float* da64 = (float*)(eb_slab + (size_t)4 * 2097152);        // 4 x 32768 f32

    wconv_kernel<<<128, 256, 0, stream>>>(w1, w2, wbf);
    enc_kernel<<<(int)(NTOK / 8), 256, 0, stream>>>(x, enc_w, enc_b, hbuf);
    k1_kernel<<<1024, 256, 0, stream>>>(lre, lim, cre, cim, dd, ls,
                                        tv_slab, eb_slab, da64);
    for (int il = 0; il < NLay; ++il) {
        lnt_kernel<<<(int)(NTOK / 32), 256, 0, stream>>>(hbuf, lns + il * Hh, lnb + il * Hh,
                                                         (uint32*)zT);
        ssm_kernel<<<dim3(256, 4), 256, 0, stream>>>(zT,
                                                     tv_slab + (size_t)il * 6291456,
                                                     eb_slab + (size_t)il * 2097152,
                                                     da64 + (size_t)il * 32768, yT);
        gated_kernel<<<dim3(256, 2), 256, 0, stream>>>(yT,
                                                       wbf + il * 65536,
                                                       wbf + 262144 + il * 65536,
                                                       b1 + il * Hh, b2 + il * Hh, hbuf);
    }
    dec_kernel<<<(int)(NTOK / 64), 256, 0, stream>>>(hbuf, dw, db, out);
}

// Round 7
// 407.616 us; speedup vs baseline: 3.2522x; 1.2329x over previous
//
#include <hip/hip_runtime.h>
#include <hip/hip_bf16.h>

#define Bb 16
#define Lq 2048
#define Hh 256
#define NLay 4
#define IND 40
#define OUTD 33

typedef unsigned int uint32;
typedef unsigned short ushort_t;

typedef short bf16x8 __attribute__((ext_vector_type(8)));
typedef float f32x4 __attribute__((ext_vector_type(4)));

__device__ __forceinline__ float sigmoidf_(float x) {
    return 1.0f / (1.0f + __expf(-x));
}
__device__ __forceinline__ float gelu_(float x) {
    float x2 = x * x;
    float u = x * fmaf(0.0713548162726f, x2, 1.5957691216057308f);
    return x * sigmoidf_(u);
}
__device__ __forceinline__ unsigned short f2bf(float f) {
    uint32 u = __float_as_uint(f);
    return (unsigned short)((u + 0x7fffu + ((u >> 16) & 1u)) >> 16);
}
__device__ __forceinline__ float bf2f(unsigned short s) {
    return __uint_as_float(((uint32)s) << 16);
}
__device__ __forceinline__ void gload16(const void* g, void* l) {
    __builtin_amdgcn_global_load_lds(
        (const __attribute__((address_space(1))) unsigned int*)g,
        (__attribute__((address_space(3))) unsigned int*)l, 16, 0, 0);
}

// ---------------- encoder ----------------
__global__ __launch_bounds__(256) void enc_kernel(const float* __restrict__ x,
                                                  const float* __restrict__ enc_w,
                                                  const float* __restrict__ enc_b,
                                                  float* __restrict__ h) {
    __shared__ float xs[8 * IND];
    int tid = threadIdx.x;
    int t0 = blockIdx.x * 8;
    for (int i = tid; i < 8 * IND; i += 256) xs[i] = x[t0 * IND + i];
    float w[IND];
    const float4* w4 = (const float4*)(enc_w + tid * IND);
#pragma unroll
    for (int c = 0; c < 10; ++c) {
        float4 v = w4[c];
        w[4 * c] = v.x; w[4 * c + 1] = v.y; w[4 * c + 2] = v.z; w[4 * c + 3] = v.w;
    }
    float bias = enc_b[tid];
    __syncthreads();
#pragma unroll
    for (int t = 0; t < 8; ++t) {
        float acc = bias;
#pragma unroll
        for (int i = 0; i < IND; ++i) acc = fmaf(xs[t * IND + i], w[i], acc);
        h[(size_t)(t0 + t) * Hh + tid] = acc;
    }
}

// ---------------- weight fp32->bf16 conversion ----------------
__global__ __launch_bounds__(256) void wconv_kernel(const float* __restrict__ w1,
                                                    const float* __restrict__ w2,
                                                    unsigned short* __restrict__ o) {
    int idx = blockIdx.x * 256 + threadIdx.x;
    for (int i = idx; i < 65536; i += 32768) {
        float4 a = ((const float4*)w1)[i];
        ushort4 u;
        u.x = f2bf(a.x); u.y = f2bf(a.y); u.z = f2bf(a.z); u.w = f2bf(a.w);
        ((ushort4*)o)[i] = u;
        float4 b4 = ((const float4*)w2)[i];
        ushort4 v;
        v.x = f2bf(b4.x); v.y = f2bf(b4.y); v.z = f2bf(b4.z); v.w = f2bf(b4.w);
        ((ushort4*)(o + 262144))[i] = v;
    }
}

// ---------------- layernorm + transpose: h[t][H] fp32 -> zT[b][h][t] bf16 (chunk-swizzled) ----------------
__global__ __launch_bounds__(256) void lnt_kernel(const float* __restrict__ h,
                                                  const float* __restrict__ scale,
                                                  const float* __restrict__ bias,
                                                  uint32* __restrict__ zT_u) {
    __shared__ float T[32 * 260];
    __shared__ float musab[64];
    __shared__ float scb[512];
    int tid = threadIdx.x, lane = tid & 63, wv = tid >> 6;
    size_t t0 = (size_t)blockIdx.x * 32;
    int b = (int)(t0 >> 11);
    int tloc = (int)(t0 & 2047);
    scb[tid] = scale[tid];
    scb[256 + tid] = bias[tid];
#pragma unroll
    for (int p = 0; p < 8; ++p) {
        int idx = tid + p * 256;
        int r = idx >> 6, c4 = idx & 63;
        float4 v = *(const float4*)&h[(t0 + r) * Hh + c4 * 4];
        *(float4*)&T[r * 260 + c4 * 4] = v;
    }
    __syncthreads();
    for (int tok = wv; tok < 32; tok += 4) {
        float4 v = *(const float4*)&T[tok * 260 + lane * 4];
        float s = (v.x + v.y) + (v.z + v.w);
        float q = fmaf(v.x, v.x, fmaf(v.y, v.y, fmaf(v.z, v.z, v.w * v.w)));
#pragma unroll
        for (int m = 1; m < 64; m <<= 1) {
            s += __shfl_xor(s, m, 64);
            q += __shfl_xor(q, m, 64);
        }
        if (lane == 0) {
            float mu = s * (1.0f / 256.0f);
            float var = q * (1.0f / 256.0f) - mu * mu;
            musab[tok] = mu;
            musab[32 + tok] = rsqrtf(var + 1e-5f);
        }
    }
    __syncthreads();
#pragma unroll
    for (int j = 0; j < 16; ++j) {
        int hh = wv * 64 + j * 4 + (lane >> 4);
        int tp = lane & 15;
        float v0 = T[(2 * tp) * 260 + hh];
        float v1 = T[(2 * tp + 1) * 260 + hh];
        float m0 = musab[2 * tp], r0 = musab[32 + 2 * tp];
        float m1 = musab[2 * tp + 1], r1 = musab[33 + 2 * tp];
        float sc = scb[hh], bi = scb[256 + hh];
        float o0 = fmaf((v0 - m0) * r0, sc, bi);
        float o1 = fmaf((v1 - m1) * r1, sc, bi);
        uint32 pk = ((uint32)f2bf(o1) << 16) | (uint32)f2bf(o0);
        uint32 u = (uint32)((tloc >> 1) + tp);
        // bake ssm's LDS chunk swizzle: 16B chunk c within 64-token tile stored at c ^ (tile&7)
        uint32 usw = (u & ~28u) | ((((u >> 2) & 7u) ^ ((u >> 5) & 7u)) << 2);
        zT_u[(size_t)(b * 256 + hh) * 1024 + usw] = pk;
    }
}

// ---------------- k1 (ALL LAYERS batched, LDS power table — no per-element transcendentals) ----------------
// tv[il][h] = [384][64]: 0..63 T_hi; 64..127 T_lo; 128..191 Vre_hi; 192..255 Vim_hi;
//                        256..319 Vre_lo; 320..383 Vim_lo
// eb[il][h] = [64][128]: E'(l,n)=2Re(dA^{l+1}), E'(l,64+n)=-2Im(dA^{l+1}); da64[il][h][2][64]
__global__ __launch_bounds__(256) void k1_kernel(const float* __restrict__ lre_p,
                                                 const float* __restrict__ lim_p,
                                                 const float* __restrict__ cre_p,
                                                 const float* __restrict__ cim_p,
                                                 const float* __restrict__ d_p,
                                                 const float* __restrict__ ls_p,
                                                 unsigned short* __restrict__ tv,
                                                 unsigned short* __restrict__ eb,
                                                 float* __restrict__ da64) {
    __shared__ float pwre[65 * 65];   // [m][n], stride 65 (bank = (m+n)%32)
    __shared__ float pwim[65 * 65];
    __shared__ float GrS[64], GiS[64], ks[64];
    int il = blockIdx.x >> 8;
    int h = blockIdx.x & 255;
    lre_p += (size_t)il * 16384; lim_p += (size_t)il * 16384;
    cre_p += (size_t)il * 16384; cim_p += (size_t)il * 16384;
    d_p += il * Hh; ls_p += il * Hh;
    tv += (size_t)il * 6291456;
    eb += (size_t)il * 2097152;
    da64 += (size_t)il * 32768;
    int tid = threadIdx.x;
    int lane = tid & 63, wv = tid >> 6;

    // ---- power table dA^m, m=0..64: wave wv covers m in [16wv, 16wv+16), lane = n ----
    {
        int n = lane;
        float lre = lre_p[h * 64 + n], lim = lim_p[h * 64 + n];
        float cre = cre_p[h * 64 + n], cim = cim_p[h * 64 + n];
        float dt = expf(ls_p[h]);
        float a = lre * dt, th = lim * dt;
        float s1, c1;
        sincosf(th, &s1, &c1);
        float er1 = expf(a);
        float dre = er1 * c1, dim = er1 * s1;           // dA
        if (wv == 0) {
            float dAre = dre, dAim = dim;
            float inv = 1.0f / (lre * lre + lim * lim);
            float dBre = ((dAre - 1.0f) * lre + dAim * lim) * inv;
            float dBim = (dAim * lre - (dAre - 1.0f) * lim) * inv;
            GrS[n] = cre * dBre - cim * dBim;
            GiS[n] = cre * dBim + cim * dBre;
        }
        float m0 = (float)(wv * 16);
        float sb, cb;
        sincosf(m0 * th, &sb, &cb);
        float erb = expf(m0 * a);
        float pre = erb * cb, pim = erb * sb;           // dA^(16wv)
#pragma unroll
        for (int mm = 0; mm < 16; ++mm) {
            int m = wv * 16 + mm;
            pwre[m * 65 + n] = pre;
            pwim[m * 65 + n] = pim;
            float nr = pre * dre - pim * dim;
            float ni = pre * dim + pim * dre;
            pre = nr; pim = ni;
        }
        if (wv == 3) {                                  // dA^64
            pwre[64 * 65 + n] = pre;
            pwim[64 * 65 + n] = pim;
            da64[h * 128 + n] = pre;
            da64[h * 128 + 64 + n] = pim;
        }
    }
    __syncthreads();

    // ---- ks[m] = 2 * sum_n (Gr*Re - Gi*Im)(dA^m) : 4 partials + shfl reduce ----
    {
        int m = tid >> 2, s = tid & 3;
        float acc = 0.0f;
#pragma unroll
        for (int i = 0; i < 16; ++i) {
            int n2 = s * 16 + i;
            acc = fmaf(GrS[n2], pwre[m * 65 + n2], fmaf(-GiS[n2], pwim[m * 65 + n2], acc));
        }
        acc += __shfl_xor(acc, 1, 64);
        acc += __shfl_xor(acc, 2, 64);
        if (s == 0) ks[m] = 2.0f * acc;
    }
    __syncthreads();

    float dh = d_p[h];
    size_t basep = (size_t)h * 24576;
#pragma unroll
    for (int i2 = 0; i2 < 16; ++i2) {   // T' hi + lo
        int e = tid + i2 * 256;
        int l = e >> 6, j = e & 63;
        float v = (j < l) ? ks[l - j] : (j == l ? ks[0] + dh : 0.0f);
        int sj = (((j >> 3) ^ (l & 7)) << 3) | (j & 7);
        unsigned short hi = f2bf(v);
        tv[basep + l * 64 + sj] = hi;
        tv[basep + (64 + l) * 64 + sj] = f2bf(v - bf2f(hi));
    }
#pragma unroll
    for (int i2 = 0; i2 < 32; ++i2) {   // V' hi + lo
        int e = tid + i2 * 256;
        int part = e >> 12, n = (e >> 6) & 63, j = e & 63;
        int m = 63 - j;
        float pre = pwre[m * 65 + n], pim = pwim[m * 65 + n];
        float v = part ? fmaf(GrS[n], pim, GiS[n] * pre) : fmaf(GrS[n], pre, -GiS[n] * pim);
        int sj = (((j >> 3) ^ (n & 7)) << 3) | (j & 7);
        unsigned short hi = f2bf(v);
        tv[basep + (size_t)(128 + part * 64 + n) * 64 + sj] = hi;
        tv[basep + (size_t)(256 + part * 64 + n) * 64 + sj] = f2bf(v - bf2f(hi));
    }
#pragma unroll
    for (int i2 = 0; i2 < 32; ++i2) {   // E'
        int e = tid + i2 * 256;
        int l = e >> 7, k = e & 127;
        int n = k & 63, m = l + 1;
        float v = (k < 64) ? 2.0f * pwre[m * 65 + n] : -2.0f * pwim[m * 65 + n];
        eb[(size_t)h * 8192 + l * 128 + ((((k >> 3) ^ (l & 7)) << 3) | (k & 7))] = f2bf(v);
    }
}

// ---------------- fused SSM (chunked scan, MFMA, 48KB LDS, per-wave f32 scratch): zT -> yT ----------------
__global__ __launch_bounds__(256, 3) void ssm_kernel(const unsigned short* __restrict__ zT,
                                                     const unsigned short* __restrict__ tv,
                                                     const unsigned short* __restrict__ eb,
                                                     const float* __restrict__ da64,
                                                     unsigned short* __restrict__ yT) {
    static __shared__ __align__(16) char LDSA[49152];
    ushort_t* Zl = (ushort_t*)LDSA;              // [128][64] Z -> later E [64][128]
    ushort_t* R1 = (ushort_t*)(LDSA + 16384);    // T [128][64] -> V_lo [128][64]
    ushort_t* R2 = (ushort_t*)(LDSA + 32768);    // V_hi [128][64]
    ushort_t* YBl = (ushort_t*)(LDSA + 16384);   // [128][72] y bounce (post-scratch)
    int tid = threadIdx.x;
    int lane = tid & 63, wv = tid >> 6;
    int lr = lane & 15, lg = lane >> 4;
    int h = blockIdx.x, mb = blockIdx.y;

    float ar = da64[h * 128 + lane];
    float ai = da64[h * 128 + 64 + lane];

    // ---- stage Z (16KB), T (16KB), V_hi (16KB) ----
#pragma unroll
    for (int it = 0; it < 4; ++it) {
        int c = it * 256 + tid;
        int r = c >> 3, s = c & 7;
        int b = mb * 4 + (r >> 5), tile = r & 31;
        size_t src = ((size_t)(b * 256 + h) << 11) + tile * 64 + s * 8;
        gload16(zT + src, (char*)Zl + (it * 256 + wv * 64) * 16);
    }
#pragma unroll
    for (int it = 0; it < 4; ++it) {    // T rows 0..127
        size_t src = (size_t)h * 24576 + (size_t)(it * 256 + tid) * 8;
        gload16(tv + src, (char*)R1 + (it * 256 + wv * 64) * 16);
    }
#pragma unroll
    for (int it = 0; it < 4; ++it) {    // V_hi = tv rows 128..255
        size_t src = (size_t)h * 24576 + 8192 + (size_t)(it * 256 + tid) * 8;
        gload16(tv + src, (char*)R2 + (it * 256 + wv * 64) * 16);
    }
    __syncthreads();   // B1

    // ---- A-fragments of Z (held in regs for GEMM1 hi+lo phases) ----
    bf16x8 afz[2][2];  // [kk][rowblock]
#pragma unroll
    for (int kk = 0; kk < 2; ++kk) {
        int row0 = wv * 32 + lr;
        int row1 = row0 + 16;
        afz[kk][0] = *(const bf16x8*)(Zl + row0 * 64 + (((kk * 4 + lg) ^ (row0 & 7)) << 3));
        afz[kk][1] = *(const bf16x8*)(Zl + row1 * 64 + (((kk * 4 + lg) ^ (row1 & 7)) << 3));
    }

    f32x4 y1[2][4], ua[2][8];
    f32x4 zf = {0.f, 0.f, 0.f, 0.f};
#pragma unroll
    for (int i = 0; i < 2; ++i) {
#pragma unroll
        for (int j = 0; j < 4; ++j) y1[i][j] = zf;
#pragma unroll
        for (int j = 0; j < 8; ++j) ua[i][j] = zf;
    }

    // ---- GEMM1a: Y1 = Z@(T_hi+T_lo);  U += Z@V_hi ----
#pragma unroll
    for (int kk = 0; kk < 2; ++kk) {
#pragma unroll
        for (int j = 0; j < 8; ++j) {   // T: j<4 hi rows, j>=4 lo rows
            int rw = (j < 4) ? ((j & 3) * 16 + lr) : (64 + (j & 3) * 16 + lr);
            bf16x8 bfr = *(const bf16x8*)(R1 + rw * 64 + (((kk * 4 + lg) ^ (lr & 7)) << 3));
            y1[0][j & 3] = __builtin_amdgcn_mfma_f32_16x16x32_bf16(afz[kk][0], bfr, y1[0][j & 3], 0, 0, 0);
            y1[1][j & 3] = __builtin_amdgcn_mfma_f32_16x16x32_bf16(afz[kk][1], bfr, y1[1][j & 3], 0, 0, 0);
        }
#pragma unroll
        for (int j = 0; j < 8; ++j) {   // V_hi: j<4 re rows 0..63, j>=4 im rows 64..127
            int rw = (j < 4) ? ((j & 3) * 16 + lr) : (64 + (j & 3) * 16 + lr);
            bf16x8 bfr = *(const bf16x8*)(R2 + rw * 64 + (((kk * 4 + lg) ^ (lr & 7)) << 3));
            ua[0][j] = __builtin_amdgcn_mfma_f32_16x16x32_bf16(afz[kk][0], bfr, ua[0][j], 0, 0, 0);
            ua[1][j] = __builtin_amdgcn_mfma_f32_16x16x32_bf16(afz[kk][1], bfr, ua[1][j], 0, 0, 0);
        }
    }
    __syncthreads();   // B2: T dead, Z-LDS dead (frags in regs)

    // ---- stage V_lo -> R1, E -> Zl ----
#pragma unroll
    for (int it = 0; it < 4; ++it) {    // V_lo = tv rows 256..383
        size_t src = (size_t)h * 24576 + 16384 + (size_t)(it * 256 + tid) * 8;
        gload16(tv + src, (char*)R1 + (it * 256 + wv * 64) * 16);
    }
#pragma unroll
    for (int it = 0; it < 4; ++it) {
        size_t src = (size_t)h * 8192 + (size_t)(it * 256 + tid) * 8;
        gload16(eb + src, (char*)Zl + (it * 256 + wv * 64) * 16);
    }
    __syncthreads();   // B3: V_lo + E arrived

    // ---- GEMM1b: U += Z@V_lo ----
#pragma unroll
    for (int kk = 0; kk < 2; ++kk)
#pragma unroll
        for (int j = 0; j < 8; ++j) {
            int rw = (j < 4) ? ((j & 3) * 16 + lr) : (64 + (j & 3) * 16 + lr);
            bf16x8 bfr = *(const bf16x8*)(R1 + rw * 64 + (((kk * 4 + lg) ^ (lr & 7)) << 3));
            ua[0][j] = __builtin_amdgcn_mfma_f32_16x16x32_bf16(afz[kk][0], bfr, ua[0][j], 0, 0, 0);
            ua[1][j] = __builtin_amdgcn_mfma_f32_16x16x32_bf16(afz[kk][1], bfr, ua[1][j], 0, 0, 0);
        }
    __syncthreads();   // B4: V dead -> R1R2 becomes per-wave scratch

    // ---- per-wave subphases: U(f32)->LDS, scan (f32 regs), W(bf16)->LDS, frags->regs ----
    uint32* Su = (uint32*)(LDSA + 16384 + wv * 8192);   // [16][128] per wave
    bf16x8 afr[2][4];
    float Sre = 0.0f, Sim = 0.0f;
#pragma unroll
    for (int i = 0; i < 2; ++i) {
        // write U exact f32 (rows local 0..15 = tiles i*16..i*16+15)
#pragma unroll
        for (int jj = 0; jj < 8; ++jj)
#pragma unroll
            for (int r = 0; r < 4; ++r) {
                int row = lg * 4 + r;
                int col = (jj & 3) * 16 + lr + ((jj >> 2) << 6);
                Su[row * 128 + (col ^ ((row & 7) << 2))] = __float_as_uint(ua[i][jj][r]);
            }
        // scan 16 tiles; W (state entering tile) written back as single bf16 in slot low-half
#pragma unroll
        for (int r = 0; r < 16; ++r) {
            int sx = (r & 7) << 2;
            int aRe = r * 128 + (lane ^ sx);
            int aIm = r * 128 + ((64 + lane) ^ sx);
            float ur = __uint_as_float(Su[aRe]);
            float ui = __uint_as_float(Su[aIm]);
            Su[aRe] = (uint32)f2bf(Sre);
            Su[aIm] = (uint32)f2bf(Sim);
            float nr = fmaf(ar, Sre, fmaf(-ai, Sim, ur));
            float ni = fmaf(ar, Sim, fmaf(ai, Sre, ui));
            Sre = nr; Sim = ni;
        }
        // build GEMM2 A-fragments (W rows = lr, k = col) into regs
#pragma unroll
        for (int kk = 0; kk < 4; ++kk) {
            int base = kk * 32 + lg * 8;
            int sx = (lr & 7) << 2;
            uint4 ua4 = *(const uint4*)&Su[lr * 128 + (base ^ sx)];
            uint4 ub4 = *(const uint4*)&Su[lr * 128 + ((base + 4) ^ sx)];
            uint4 pk;
            pk.x = __builtin_amdgcn_perm(ua4.y, ua4.x, 0x05040100u);
            pk.y = __builtin_amdgcn_perm(ua4.w, ua4.z, 0x05040100u);
            pk.z = __builtin_amdgcn_perm(ub4.y, ub4.x, 0x05040100u);
            pk.w = __builtin_amdgcn_perm(ub4.w, ub4.z, 0x05040100u);
            afr[i][kk] = *(bf16x8*)&pk;
        }
    }
    __syncthreads();   // B5: all scratch phases done

    // ---- GEMM2: Y2 = W @ E' ----
    f32x4 y2[2][4];
#pragma unroll
    for (int i = 0; i < 2; ++i)
#pragma unroll
        for (int j = 0; j < 4; ++j) y2[i][j] = zf;
#pragma unroll
    for (int kk = 0; kk < 4; ++kk)
#pragma unroll
        for (int j = 0; j < 4; ++j) {
            int rw = j * 16 + lr;
            bf16x8 bfr = *(const bf16x8*)(Zl + rw * 128 + (((kk * 4 + lg) ^ (rw & 7)) << 3));
            y2[0][j] = __builtin_amdgcn_mfma_f32_16x16x32_bf16(afr[0][kk], bfr, y2[0][j], 0, 0, 0);
            y2[1][j] = __builtin_amdgcn_mfma_f32_16x16x32_bf16(afr[1][kk], bfr, y2[1][j], 0, 0, 0);
        }

    // ---- epilogue: y = gelu(Y1 + Y2) -> bounce (overlays scratch; safe post-B5) ----
#pragma unroll
    for (int i = 0; i < 2; ++i)
#pragma unroll
        for (int j = 0; j < 4; ++j)
#pragma unroll
            for (int r = 0; r < 4; ++r) {
                int row = wv * 32 + i * 16 + lg * 4 + r;
                int col = j * 16 + lr;
                float y = y1[i][j][r] + y2[i][j][r];
                YBl[row * 72 + col] = f2bf(gelu_(y));
            }
    __syncthreads();   // B6

    // ---- coalesced flush to yT [b][h][t] ----
#pragma unroll
    for (int it = 0; it < 4; ++it) {
        int c = it * 256 + tid;
        int row = c >> 3, c8 = c & 7;
        int b = mb * 4 + (row >> 5), tile = row & 31;
        uint4 v = *(const uint4*)((const char*)YBl + row * 144 + c8 * 16);
        *(uint4*)(yT + (((size_t)(b * 256 + h)) << 11) + tile * 64 + c8 * 8) = v;
    }
}

// ---------------- gated MFMA GEMM + residual, reading yT[b][h][t] directly ----------------
// A-tile staged subtiled [hblk 8][tc 8] x [4h][16t] (128B blocks) via per-lane-src gload16;
// A-fragments built with ds_read_b64_tr_b16 (lane lr = t-col, 4 h's per read).
__global__ __launch_bounds__(256, 2) void gated_kernel(const unsigned short* __restrict__ yT,
                                                       const unsigned short* __restrict__ w1b,
                                                       const unsigned short* __restrict__ w2b,
                                                       const float* __restrict__ b1,
                                                       const float* __restrict__ b2,
                                                       float* __restrict__ h) {
    __shared__ __align__(16) unsigned short Al[4096];
    __shared__ __align__(16) unsigned short W1l[4096];
    __shared__ __align__(16) unsigned short W2l[4096];
    int tid = threadIdx.x;
    int lane = tid & 63;
    int wv = tid >> 6;
    int wm = wv >> 1, wn = wv & 1;
    int lr = lane & 15, lg = lane >> 4;
    size_t t0 = (size_t)blockIdx.x * 128;
    int bsel = (int)(t0 >> 11);
    int tloc0 = (int)(t0 & 2047);
    int g0 = blockIdx.y * 128;

    f32x4 acc1[4][4], acc2[4][4];
    f32x4 zf = {0.f, 0.f, 0.f, 0.f};
#pragma unroll
    for (int i = 0; i < 4; ++i)
#pragma unroll
        for (int j = 0; j < 4; ++j) { acc1[i][j] = zf; acc2[i][j] = zf; }

    uint32 abase = (uint32)(size_t)(__attribute__((address_space(3))) unsigned short*)Al;

    for (int kt = 0; kt < 8; ++kt) {
        __syncthreads();
        int k0 = kt * 32;
#pragma unroll
        for (int p = 0; p < 2; ++p) {
            int s = p * 256 + tid;
            int ldsoff = (p * 256 + wv * 64) * 16;
            // A: slot s -> block bi=(hblk*8+tc), within-block 16B slot w
            {
                int bi = s >> 3, w = s & 7;
                int hblk = bi >> 3, tc = bi & 7;
                int ha = hblk * 4 + (w >> 1);
                int toff = tc * 16 + (w & 1) * 8;
                gload16(yT + (((size_t)(bsel * 256 + k0 + ha)) << 11) + tloc0 + toff,
                        (char*)Al + ldsoff);
            }
            // W: paired-row (128B line) chunk swizzle ^(L&7), baked into per-lane src
            {
                int L = s >> 3, cs = s & 7;
                int cu = cs ^ (L & 7);
                int row = L * 2 + (cu >> 2), q = cu & 3;
                gload16(w1b + (size_t)(g0 + row) * 256 + k0 + q * 8, (char*)W1l + ldsoff);
                gload16(w2b + (size_t)(g0 + row) * 256 + k0 + q * 8, (char*)W2l + ldsoff);
            }
        }
        __syncthreads();
        bf16x8 a[4], f1[4], f2[4];
#pragma unroll
        for (int i = 0; i < 4; ++i) {
            int tc = wm * 4 + i;
            uint32 a0 = abase + (uint32)((lg * 2 * 8 + tc) * 128 + lr * 8);
            uint32 a1 = a0 + 1024;   // next hblk
            uint2 d0, d1;
            asm volatile("ds_read_b64_tr_b16 %0, %2\n\t"
                         "ds_read_b64_tr_b16 %1, %3\n\t"
                         "s_waitcnt lgkmcnt(0)"
                         : "=&v"(d0), "=&v"(d1)
                         : "v"(a0), "v"(a1));
            uint4 pk;
            pk.x = d0.x; pk.y = d0.y; pk.z = d1.x; pk.w = d1.y;
            a[i] = *(bf16x8*)&pk;
        }
#pragma unroll
        for (int j = 0; j < 4; ++j) {
            int row = wn * 64 + j * 16 + lr;
            int wadr = (row >> 1) * 64 + ((((row & 1) * 4 + lg) ^ ((row >> 1) & 7)) << 3);
            f1[j] = *(const bf16x8*)(W1l + wadr);
            f2[j] = *(const bf16x8*)(W2l + wadr);
        }
#pragma unroll
        for (int i = 0; i < 4; ++i)
#pragma unroll
            for (int j = 0; j < 4; ++j) {
                acc1[i][j] = __builtin_amdgcn_mfma_f32_16x16x32_bf16(a[i], f1[j], acc1[i][j], 0, 0, 0);
                acc2[i][j] = __builtin_amdgcn_mfma_f32_16x16x32_bf16(a[i], f2[j], acc2[i][j], 0, 0, 0);
            }
    }

    float bb1[4], bb2[4];
#pragma unroll
    for (int j = 0; j < 4; ++j) {
        int g = g0 + wn * 64 + j * 16 + lr;
        bb1[j] = b1[g];
        bb2[j] = b2[g];
    }
#pragma unroll
    for (int i = 0; i < 4; ++i)
#pragma unroll
        for (int j = 0; j < 4; ++j) {
            int g = g0 + wn * 64 + j * 16 + lr;
#pragma unroll
            for (int r = 0; r < 4; ++r) {
                size_t t = t0 + wm * 64 + i * 16 + lg * 4 + r;
                float p1 = acc1[i][j][r] + bb1[j];
                float p2 = acc2[i][j][r] + bb2[j];
                float* hp = &h[t * Hh + g];
                *hp = fmaf(p1, sigmoidf_(p2), *hp);
            }
        }
}

// ---------------- decoder ----------------
__global__ __launch_bounds__(256) void dec_kernel(const float* __restrict__ h,
                                                  const float* __restrict__ dec_w,
                                                  const float* __restrict__ dec_b,
                                                  float* __restrict__ out) {
    __shared__ float wT[256][36];
    __shared__ float hs[64][20];
    int tid = threadIdx.x;
    for (int idx = tid; idx < OUTD * Hh; idx += 256) {
        int o = idx >> 8, k = idx & 255;
        wT[k][o] = dec_w[idx];
    }
    size_t t0 = (size_t)blockIdx.x * 64;
    int tl = tid & 63, og = tid >> 6;
    float acc[9];
#pragma unroll
    for (int j = 0; j < 9; ++j) acc[j] = 0.0f;
    int i = tid >> 2, c = (tid & 3) * 4;
    for (int kt = 0; kt < 16; ++kt) {
        __syncthreads();
        *(float4*)&hs[i][c] = *(const float4*)&h[(t0 + i) * Hh + kt * 16 + c];
        __syncthreads();
#pragma unroll
        for (int k2 = 0; k2 < 16; ++k2) {
            float a = hs[tl][k2];
            int kk = kt * 16 + k2;
#pragma unroll
            for (int j = 0; j < 9; ++j) acc[j] = fmaf(a, wT[kk][og + 4 * j], acc[j]);
        }
    }
#pragma unroll
    for (int j = 0; j < 9; ++j) {
        int o = og + 4 * j;
        if (o < OUTD) out[(t0 + tl) * OUTD + o] = acc[j] + dec_b[o];
    }
}

extern "C" void kernel_launch(void* const* d_in, const int* in_sizes, int n_in,
                              void* d_out, int out_size, void* d_ws, size_t ws_size,
                              hipStream_t stream) {
    const float* x = (const float*)d_in[0];
    const float* enc_w = (const float*)d_in[1];
    const float* enc_b = (const float*)d_in[2];
    const float* lre = (const float*)d_in[3];
    const float* lim = (const float*)d_in[4];
    const float* cre = (const float*)d_in[5];
    const float* cim = (const float*)d_in[6];
    const float* dd = (const float*)d_in[7];
    const float* ls = (const float*)d_in[8];
    const float* lns = (const float*)d_in[9];
    const float* lnb = (const float*)d_in[10];
    const float* w1 = (const float*)d_in[11];
    const float* b1 = (const float*)d_in[12];
    const float* w2 = (const float*)d_in[13];
    const float* b2 = (const float*)d_in[14];
    const float* dw = (const float*)d_in[15];
    const float* db = (const float*)d_in[16];
    float* out = (float*)d_out;

    const size_t NTOK = (size_t)Bb * Lq;
    float* hbuf = (float*)d_ws;                                   // 32MB fp32
    unsigned short* zT = (unsigned short*)(hbuf + NTOK * Hh);     // 16MB bf16 [b][h][t] (swizzled chunks)
    unsigned short* yT = zT + NTOK * Hh;                          // 16MB bf16 [b][h][t] (linear)
    unsigned short* wbf = yT + NTOK * Hh;                         // 1MB bf16 gated weights
    unsigned short* tv_slab = wbf + 524288;                       // 4 layers x 6291456 ush = 50MB
    unsigned short* eb_slab = tv_slab + (size_t)4 * 6291456;      // 4 x 2097152 ush = 17MB
    float* da64 = (float*)(eb_slab + (size_t)4 * 2097152);        // 4 x 32768 f32

    wconv_kernel<<<128, 256, 0, stream>>>(w1, w2, wbf);
    enc_kernel<<<(int)(NTOK / 8), 256, 0, stream>>>(x, enc_w, enc_b, hbuf);
    k1_kernel<<<1024, 256, 0, stream>>>(lre, lim, cre, cim, dd, ls,
                                        tv_slab, eb_slab, da64);
    for (int il = 0; il < NLay; ++il) {
        lnt_kernel<<<(int)(NTOK / 32), 256, 0, stream>>>(hbuf, lns + il * Hh, lnb + il * Hh,
                                                         (uint32*)zT);
        ssm_kernel<<<dim3(256, 4), 256, 0, stream>>>(zT,
                                                     tv_slab + (size_t)il * 6291456,
                                                     eb_slab + (size_t)il * 2097152,
                                                     da64 + (size_t)il * 32768, yT);
        gated_kernel<<<dim3(256, 2), 256, 0, stream>>>(yT,
                                                       wbf + il * 65536,
                                                       wbf + 262144 + il * 65536,
                                                       b1 + il * Hh, b2 + il * Hh, hbuf);
    }
    dec_kernel<<<(int)(NTOK / 64), 256, 0, stream>>>(hbuf, dw, db, out);
}